// Round 5
// baseline (2592.671 us; speedup 1.0000x reference)
//
#include <hip/hip_runtime.h>
#include <math.h>

#define H 128
#define SSTEPS 3
#define NE 131072
#define NT 5
#define NCELL 16384
#define NCLU 1088
#define G4 512
#define AKT 28       // Apack kt count (896 K-cols / 32)
#define EB 128

typedef unsigned short u16;
typedef unsigned int u32;
typedef __attribute__((ext_vector_type(8))) short short8;
typedef __attribute__((ext_vector_type(8))) unsigned short ushort8;
typedef __attribute__((ext_vector_type(4))) float f32x4;

__device__ __forceinline__ u16 f2bf(float f) {
    unsigned int u = __float_as_uint(f);
    u += 0x7fffu + ((u >> 16) & 1u);
    return (u16)(u >> 16);
}
__device__ __forceinline__ float bf2f(u16 h) {
    return __uint_as_float(((unsigned int)h) << 16);
}

// ---------------- avg of class embeddings 1..16 per batch ----------------
__global__ __launch_bounds__(128) void k_avg(const float* __restrict__ emb,
                                             float* __restrict__ avg) {
    int b = blockIdx.x, hc = threadIdx.x;
    float s = 0.f;
#pragma unroll
    for (int r = 1; r <= 16; ++r) s += emb[(b * 17 + r) * H + hc];
    avg[b * H + hc] = s * (1.0f / 16.0f);
}

// ---------------- init: cell_x -> Apack kt 0:4 (hi/lo); zero rnn_h, cst ----------------
__global__ __launch_bounds__(256) void k_init(const int* __restrict__ q,
                                              const float* __restrict__ emb,
                                              const float* __restrict__ avg,
                                              u16* __restrict__ Ap, size_t aplane,
                                              float* __restrict__ rnn_h,
                                              float* __restrict__ cst) {
    __shared__ float sx[16][132];
    int mtile = blockIdx.x, tid = threadIdx.x;
#pragma unroll
    for (int e = 0; e < 8; ++e) {
        int idx = e * 256 + tid;
        int row = idx >> 7, c = idx & 127;
        int grow = mtile * 16 + row;
        int b = grow >> 8;
        int qi = q[grow];
        const float* src = (qi == 0) ? (avg + b * H) : (emb + (b * 17 + qi) * H);
        float v = src[c];
        sx[row][c] = v;
        rnn_h[(size_t)grow * H + c] = 0.f;
        cst[(size_t)grow * H + c] = 0.f;
    }
    __syncthreads();
    int kt = tid >> 6, lane = tid & 63;
    int row = lane & 15, c0 = kt * 32 + ((lane >> 4) << 3);
    ushort8 hh, ll;
#pragma unroll
    for (int i = 0; i < 8; ++i) {
        float x = sx[row][c0 + i];
        u16 h = f2bf(x);
        hh[i] = h;
        ll[i] = f2bf(x - bf2f(h));
    }
    size_t fo = ((size_t)(mtile * AKT + kt) * 64 + lane) * 8;
    *reinterpret_cast<ushort8*>(Ap + fo) = hh;
    *reinterpret_cast<ushort8*>(Ap + aplane + fo) = ll;
}

// ---------------- edge dst counting sort: zero, count, scan, scatter ----------------
__global__ __launch_bounds__(256) void k_zerocnt(u32* __restrict__ cnt) {
    cnt[blockIdx.x * 256 + threadIdx.x] = 0;
}
__global__ __launch_bounds__(256) void k_count(const int* __restrict__ edges,
                                               u32* __restrict__ cnt) {
    int gid = blockIdx.x * 256 + threadIdx.x;     // NT*NE
    int t = gid >> 17, e = gid & (NE - 1);
    int dst = edges[(t * 2 + 1) * NE + e];
    atomicAdd(&cnt[t * NCELL + dst], 1u);
}
__global__ __launch_bounds__(256) void k_scan(const u32* __restrict__ cnt,
                                              u32* __restrict__ cursor) {
    __shared__ u32 ls[256];
    int t = blockIdx.x, tid = threadIdx.x;
    const u32* c = cnt + t * NCELL;
    u32 vals[64];
    u32 s = 0;
    int base = tid * 64;
#pragma unroll
    for (int i = 0; i < 64; ++i) { vals[i] = c[base + i]; s += vals[i]; }
    ls[tid] = s;
    __syncthreads();
    for (int d = 1; d < 256; d <<= 1) {
        u32 v = (tid >= d) ? ls[tid - d] : 0;
        __syncthreads();
        ls[tid] += v;
        __syncthreads();
    }
    u32 run = ls[tid] - s;   // exclusive prefix for this chunk
#pragma unroll
    for (int i = 0; i < 64; ++i) {
        cursor[t * NCELL + base + i] = run;
        run += vals[i];
    }
}
__global__ __launch_bounds__(256) void k_scatter(const int* __restrict__ edges,
                                                 u32* __restrict__ cursor,
                                                 int* __restrict__ perm) {
    int gid = blockIdx.x * 256 + threadIdx.x;     // NT*NE
    int t = gid >> 17, e = gid & (NE - 1);
    int dst = edges[(t * 2 + 1) * NE + e];
    u32 slot = atomicAdd(&cursor[t * NCELL + dst], 1u);
    perm[t * NE + slot] = e;
}
// NOTE: after k_scatter, cursor[t*NCELL+d] == end offset of d's run; start = end - cnt.

// ---------------- fp32 GEMM -> bf16 out (Ps0 only; tiny) ----------------
__global__ __launch_bounds__(256) void k_gemm32(const float* __restrict__ A, int lda,
                                                const float* __restrict__ B, int ldb,
                                                u16* __restrict__ C, int ldc, int K) {
    __shared__ float As[64][33];
    __shared__ float Bs[32][64];
    int tid = threadIdx.x;
    int ty = tid >> 4, tx = tid & 15;
    int rbase = blockIdx.x * 64, cbase = blockIdx.y * 64;
    float acc[4][4] = {};
    for (int k0 = 0; k0 < K; k0 += 32) {
        __syncthreads();
#pragma unroll
        for (int i = 0; i < 8; ++i) {
            int id = tid + i * 256;
            int r = id >> 5, c = id & 31;
            As[r][c] = A[(size_t)(rbase + r) * lda + k0 + c];
        }
#pragma unroll
        for (int i = 0; i < 8; ++i) {
            int id = tid + i * 256;
            int r = id >> 6, c = id & 63;
            Bs[r][c] = B[(size_t)(k0 + r) * ldb + cbase + c];
        }
        __syncthreads();
#pragma unroll 8
        for (int kk = 0; kk < 32; ++kk) {
            float a[4], bv[4];
#pragma unroll
            for (int i = 0; i < 4; ++i) a[i] = As[ty * 4 + i][kk];
#pragma unroll
            for (int j = 0; j < 4; ++j) bv[j] = Bs[kk][tx * 4 + j];
#pragma unroll
            for (int i = 0; i < 4; ++i)
#pragma unroll
                for (int j = 0; j < 4; ++j) acc[i][j] = fmaf(a[i], bv[j], acc[i][j]);
        }
    }
#pragma unroll
    for (int i = 0; i < 4; ++i)
#pragma unroll
        for (int j = 0; j < 4; ++j)
            C[(size_t)(rbase + ty * 4 + i) * ldc + cbase + tx * 4 + j] = f2bf(acc[i][j]);
}

// ---------------- W2/W3/W4 -> fragment-packed bf16 hi/lo ----------------
__global__ __launch_bounds__(256) void k_prepw(const float* __restrict__ W2,
                                               const float* __restrict__ W3,
                                               const float* __restrict__ W4,
                                               u16* __restrict__ WF) {
    int bid = blockIdx.x;                  // 240 = 5*3*2*8
    int t = bid / 48;
    int l = (bid / 16) % 3;
    int p = (bid / 8) % 2;
    int nt = bid % 8;
    int tid = threadIdx.x;
    int ks = tid >> 6, lane = tid & 63;
    const float* W = (l == 0 ? W2 : l == 1 ? W3 : W4) + t * 16384;
    int n = nt * 16 + (lane & 15);
    int kb = ks * 32 + (lane >> 4) * 8;
    ushort8 o;
#pragma unroll
    for (int i = 0; i < 8; ++i) {
        float w = W[(size_t)(kb + i) * H + n];
        u16 h = f2bf(w);
        o[i] = (p == 0) ? h : f2bf(w - bf2f(h));
    }
    size_t base = ((size_t)((((t * 3 + l) * 2 + p) * 8 + nt) * 4 + ks) * 64 + lane) * 8;
    *reinterpret_cast<ushort8*>(WF + base) = o;
}

// ---------------- pack [Wih;Whh] -> B-frags hi/lo ----------------
__global__ __launch_bounds__(256) void k_packBw(const float* __restrict__ Wih,
                                                const float* __restrict__ Whh,
                                                u16* __restrict__ Bw, size_t bplane) {
    int nt = blockIdx.x;                           // 32
    int kt = blockIdx.y * 4 + (threadIdx.x >> 6);  // grid.y=7 -> 0..27
    int lane = threadIdx.x & 63;
    int n = nt * 16 + (lane & 15);
    int k0 = kt * 32 + ((lane >> 4) << 3);
    ushort8 hh, ll;
#pragma unroll
    for (int i = 0; i < 8; ++i) {
        int k = k0 + i;
        float wv = (k < 768) ? Wih[(size_t)k * G4 + n] : Whh[(size_t)(k - 768) * G4 + n];
        u16 h = f2bf(wv);
        hh[i] = h;
        ll[i] = f2bf(wv - bf2f(h));
    }
    size_t fo = ((size_t)(nt * AKT + kt) * 64 + lane) * 8;
    *reinterpret_cast<ushort8*>(Bw + fo) = hh;
    *reinterpret_cast<ushort8*>(Bw + bplane + fo) = ll;
}

// ---------------- pack projection weights (from W1) -> B-frags hi/lo ----------------
__global__ __launch_bounds__(256) void k_packBp(const float* __restrict__ W1,
                                                u16* __restrict__ Bp, size_t bplane) {
    int nt = blockIdx.x;               // 72
    int kt = threadIdx.x >> 6;         // 0..3
    int lane = threadIdx.x & 63;
    int n = nt * 16 + (lane & 15);
    int k0 = kt * 32 + ((lane >> 4) << 3);
    int t, roff, j;
    if (n < 640) { t = n >> 7; j = n & 127; roff = 128; }
    else { int m = n - 640; t = (m >> 7) + 1; j = m & 127; roff = 0; }
    ushort8 hh, ll;
#pragma unroll
    for (int i = 0; i < 8; ++i) {
        float wv = W1[((size_t)t * 256 + roff + k0 + i) * H + j];
        u16 h = f2bf(wv);
        hh[i] = h;
        ll[i] = f2bf(wv - bf2f(h));
    }
    size_t fo = ((size_t)(nt * 4 + kt) * 64 + lane) * 8;
    *reinterpret_cast<ushort8*>(Bp + fo) = hh;
    *reinterpret_cast<ushort8*>(Bp + bplane + fo) = ll;
}

// ---------------- MFMA GEMM, 3-term split bf16, frag inputs, no LDS ----------------
__global__ __launch_bounds__(256) void k_gemm_bf(const u16* __restrict__ Ap, size_t aplane,
                                                 int aktbase,
                                                 const u16* __restrict__ Bp, size_t bplane,
                                                 int bKT, int nkt,
                                                 float* __restrict__ Cf, u16* __restrict__ Ch,
                                                 int ldc) {
    int tid = threadIdx.x;
    int w = tid >> 6, lane = tid & 63;
    int wr = w >> 1, wc = w & 1;
    int mtb = blockIdx.x * 8 + wr * 4;
    int ntb = blockIdx.y * 8 + wc * 4;
    f32x4 acc[4][4] = {};
    for (int kk = 0; kk < nkt; ++kk) {
        short8 Ah[4], Al[4], Bh[4], Bl[4];
#pragma unroll
        for (int m = 0; m < 4; ++m) {
            size_t fo = ((size_t)((mtb + m) * AKT + aktbase + kk) * 64 + lane) * 8;
            Ah[m] = *reinterpret_cast<const short8*>(Ap + fo);
            Al[m] = *reinterpret_cast<const short8*>(Ap + aplane + fo);
        }
#pragma unroll
        for (int n = 0; n < 4; ++n) {
            size_t fo = ((size_t)((ntb + n) * bKT + kk) * 64 + lane) * 8;
            Bh[n] = *reinterpret_cast<const short8*>(Bp + fo);
            Bl[n] = *reinterpret_cast<const short8*>(Bp + bplane + fo);
        }
#pragma unroll
        for (int m = 0; m < 4; ++m)
#pragma unroll
            for (int n = 0; n < 4; ++n) {
                acc[m][n] = __builtin_amdgcn_mfma_f32_16x16x32_bf16(Ah[m], Bh[n], acc[m][n], 0, 0, 0);
                acc[m][n] = __builtin_amdgcn_mfma_f32_16x16x32_bf16(Ah[m], Bl[n], acc[m][n], 0, 0, 0);
                acc[m][n] = __builtin_amdgcn_mfma_f32_16x16x32_bf16(Al[m], Bh[n], acc[m][n], 0, 0, 0);
            }
    }
#pragma unroll
    for (int m = 0; m < 4; ++m)
#pragma unroll
        for (int r = 0; r < 4; ++r) {
            int row = (mtb + m) * 16 + (lane >> 4) * 4 + r;
#pragma unroll
            for (int n = 0; n < 4; ++n) {
                int col = (ntb + n) * 16 + (lane & 15);
                float v = acc[m][n][r];
                if (Ch) Ch[(size_t)row * ldc + col] = f2bf(v);
                else Cf[(size_t)row * ldc + col] = v;
            }
        }
}

// ---------------- per-edge MLP for ONE edge type: sorted edges, streaming z4 out ----------------
__global__ __launch_bounds__(256, 4) void k_edge(const int* __restrict__ edges,
                                                 const int* __restrict__ perm,
                                                 const u16* __restrict__ P,
                                                 const u16* __restrict__ Ps0,
                                                 const u16* __restrict__ WF,
                                                 const float* __restrict__ bb1,
                                                 const float* __restrict__ bb2,
                                                 const float* __restrict__ bb3,
                                                 const float* __restrict__ bb4,
                                                 u16* __restrict__ z4,
                                                 int t) {
    __shared__ u16 zh[EB * H];    // 32KB, 16B-chunk XOR swizzle
    int tid = threadIdx.x;
    int w = tid >> 6, lane = tid & 63;
    int ebase = blockIdx.x * EB;

    // ---- layer 1 (edges in dst-sorted order via perm) ----
    {
        int row = tid >> 1, half = tid & 1;
        int eo = perm[t * NE + ebase + row];
        int sn = edges[(t * 2) * NE + eo];
        int dn = edges[(t * 2 + 1) * NE + eo];
        const u16* ps = (t == 0) ? Ps0 + (size_t)sn * H
                                 : P + (size_t)sn * 1152 + 640 + (t - 1) * H;
        const u16* pd = P + (size_t)dn * 1152 + t * H;
        const float* bb = bb1 + t * H;
#pragma unroll
        for (int cc = 0; cc < 8; ++cc) {
            int c8 = half * 8 + cc;
            ushort8 a = *reinterpret_cast<const ushort8*>(ps + c8 * 8);
            ushort8 d = *reinterpret_cast<const ushort8*>(pd + c8 * 8);
            float4 b0 = *reinterpret_cast<const float4*>(bb + c8 * 8);
            float4 b1v = *reinterpret_cast<const float4*>(bb + c8 * 8 + 4);
            float bv[8] = {b0.x, b0.y, b0.z, b0.w, b1v.x, b1v.y, b1v.z, b1v.w};
            ushort8 hh;
#pragma unroll
            for (int i = 0; i < 8; ++i)
                hh[i] = f2bf(fmaxf(bf2f(a[i]) + bf2f(d[i]) + bv[i], 0.f));
            *reinterpret_cast<ushort8*>(&zh[row * H + ((c8 ^ (row & 7)) << 3)]) = hh;
        }
    }
    __syncthreads();

    const u16* wfbase = WF + (size_t)(t * 3) * 32768;
    f32x4 acc[8][2];
    short8 Bh[2][4], Bl[2][4];

#pragma unroll 1
    for (int l = 0; l < 3; ++l) {
        const u16* wl = wfbase + l * 32768;
#pragma unroll
        for (int ng = 0; ng < 2; ++ng)
#pragma unroll
            for (int ks = 0; ks < 4; ++ks) {
                int nt = 2 * w + ng;
                Bh[ng][ks] = *reinterpret_cast<const short8*>(wl + ((nt * 4 + ks) * 64 + lane) * 8);
                Bl[ng][ks] = *reinterpret_cast<const short8*>(wl + ((32 + nt * 4 + ks) * 64 + lane) * 8);
            }
#pragma unroll
        for (int mt = 0; mt < 8; ++mt)
#pragma unroll
            for (int ng = 0; ng < 2; ++ng)
                acc[mt][ng] = (f32x4){0.f, 0.f, 0.f, 0.f};
#pragma unroll
        for (int mt = 0; mt < 8; ++mt) {
            short8 Ah[4];
            int rr = mt * 16 + (lane & 15);
#pragma unroll
            for (int ks = 0; ks < 4; ++ks) {
                int ch = ks * 4 + (lane >> 4);
                Ah[ks] = *reinterpret_cast<const short8*>(&zh[rr * H + ((ch ^ (rr & 7)) << 3)]);
            }
#pragma unroll
            for (int ng = 0; ng < 2; ++ng)
#pragma unroll
                for (int ks = 0; ks < 4; ++ks) {
                    acc[mt][ng] = __builtin_amdgcn_mfma_f32_16x16x32_bf16(Ah[ks], Bh[ng][ks], acc[mt][ng], 0, 0, 0);
                    acc[mt][ng] = __builtin_amdgcn_mfma_f32_16x16x32_bf16(Ah[ks], Bl[ng][ks], acc[mt][ng], 0, 0, 0);
                }
        }
        if (l < 2) {
            __syncthreads();   // all reads of zh done
            const float* bb = (l == 0 ? bb2 : bb3) + t * H;
            float bi[2];
#pragma unroll
            for (int ng = 0; ng < 2; ++ng) bi[ng] = bb[(2 * w + ng) * 16 + (lane & 15)];
#pragma unroll
            for (int mt = 0; mt < 8; ++mt)
#pragma unroll
                for (int ng = 0; ng < 2; ++ng) {
                    int col = (2 * w + ng) * 16 + (lane & 15);
#pragma unroll
                    for (int r = 0; r < 4; ++r) {
                        int rr = mt * 16 + (lane >> 4) * 4 + r;
                        float x = fmaxf(acc[mt][ng][r] + bi[ng], 0.f);
                        zh[rr * H + (((col >> 3) ^ (rr & 7)) << 3) + (col & 7)] = f2bf(x);
                    }
                }
            __syncthreads();   // writes visible
        } else {
            // layer 4: streaming store of z4 rows (sorted edge order), no relu
            const float* bb = bb4 + t * H;
            float bi[2];
#pragma unroll
            for (int ng = 0; ng < 2; ++ng) bi[ng] = bb[(2 * w + ng) * 16 + (lane & 15)];
#pragma unroll
            for (int mt = 0; mt < 8; ++mt)
#pragma unroll
                for (int ng = 0; ng < 2; ++ng) {
                    int col = (2 * w + ng) * 16 + (lane & 15);
#pragma unroll
                    for (int r = 0; r < 4; ++r) {
                        int rr = mt * 16 + (lane >> 4) * 4 + r;
                        z4[(size_t)(ebase + rr) * H + col] = f2bf(acc[mt][ng][r] + bi[ng]);
                    }
                }
        }
    }
}

// ---------------- segment-reduce sorted z4 runs -> Ap msg frags (one type) ----------------
__global__ __launch_bounds__(256) void k_msgreduce(const u16* __restrict__ z4,
                                                   const u32* __restrict__ cnt,
                                                   const u32* __restrict__ cursor,
                                                   u16* __restrict__ Ap, size_t aplane,
                                                   int t) {
    __shared__ float sacc[16][132];
    int mtile = blockIdx.x, tid = threadIdx.x;
    int rh = tid >> 7, c = tid & 127;          // 2 rows in flight
#pragma unroll 1
    for (int rp = 0; rp < 8; ++rp) {
        int row = rp * 2 + rh;
        int d = mtile * 16 + row;
        u32 end = cursor[t * NCELL + d];
        u32 start = end - cnt[t * NCELL + d];
        float a = 0.f;
        const u16* zb = z4 + c;
        for (u32 e = start; e < end; ++e)
            a += bf2f(zb[(size_t)e * H]);
        sacc[row][c] = a;
    }
    __syncthreads();
    int q = tid >> 6, lane = tid & 63;
    int row = lane & 15;
    int c0 = q * 32 + ((lane >> 4) << 3);
    ushort8 hh, ll;
#pragma unroll
    for (int i = 0; i < 8; ++i) {
        float x = sacc[row][c0 + i];
        u16 h = f2bf(x);
        hh[i] = h;
        ll[i] = f2bf(x - bf2f(h));
    }
    size_t fo = ((size_t)(mtile * AKT + 4 + t * 4 + q) * 64 + lane) * 8;
    *reinterpret_cast<ushort8*>(Ap + fo) = hh;
    *reinterpret_cast<ushort8*>(Ap + aplane + fo) = ll;
}

// ---------------- LSTM pointwise + h frag pack (kt 24:28) ----------------
__global__ __launch_bounds__(256) void k_lstm(const float* __restrict__ gates,
                                              float* __restrict__ cst,
                                              float* __restrict__ rnn_h,
                                              u16* __restrict__ Ap, size_t aplane) {
    __shared__ float sh[16][132];
    int mtile = blockIdx.x, tid = threadIdx.x;
#pragma unroll
    for (int e = 0; e < 8; ++e) {
        int idx = e * 256 + tid;
        int row = idx >> 7, c = idx & 127;
        int grow = mtile * 16 + row;
        const float* g = gates + (size_t)grow * G4;
        float ig = g[c], fg = g[128 + c], gg = g[256 + c], og = g[384 + c];
        size_t ci = (size_t)grow * H + c;
        float c_old = cst[ci];
        float i_s = 1.f / (1.f + expf(-ig));
        float f_s = 1.f / (1.f + expf(-fg));
        float o_s = 1.f / (1.f + expf(-og));
        float c_new = f_s * c_old + i_s * tanhf(gg);
        float h_new = o_s * tanhf(c_new);
        cst[ci] = c_new;
        rnn_h[ci] = h_new;
        sh[row][c] = h_new;
    }
    __syncthreads();
    int kt = tid >> 6, lane = tid & 63;
    int row = lane & 15, c0 = kt * 32 + ((lane >> 4) << 3);
    ushort8 hh, ll;
#pragma unroll
    for (int i = 0; i < 8; ++i) {
        float x = sh[row][c0 + i];
        u16 h = f2bf(x);
        hh[i] = h;
        ll[i] = f2bf(x - bf2f(h));
    }
    size_t fo = ((size_t)(mtile * AKT + 24 + kt) * 64 + lane) * 8;
    *reinterpret_cast<ushort8*>(Ap + fo) = hh;
    *reinterpret_cast<ushort8*>(Ap + aplane + fo) = ll;
}

// ---------------- logits ----------------
__global__ __launch_bounds__(256) void k_logits(const float* __restrict__ h,
                                                const float* __restrict__ oemb,
                                                float* __restrict__ out) {
    __shared__ float oe[17][129];
    int b = blockIdx.x, tid = threadIdx.x;
    for (int id = tid; id < 17 * 128; id += 256) {
        int r = id >> 7, c = id & 127;
        oe[r][c] = oemb[(b * 17 + r) * H + c];
    }
    __syncthreads();
    const float* hr = h + (size_t)(b * 256 + tid) * H;
    float acc[17] = {};
    for (int v = 0; v < 32; ++v) {
        float4 hv = reinterpret_cast<const float4*>(hr)[v];
#pragma unroll
        for (int cls = 0; cls < 17; ++cls) {
            acc[cls] = fmaf(hv.x, oe[cls][v * 4 + 0],
                       fmaf(hv.y, oe[cls][v * 4 + 1],
                       fmaf(hv.z, oe[cls][v * 4 + 2],
                       fmaf(hv.w, oe[cls][v * 4 + 3], acc[cls]))));
        }
    }
    float* op = out + (size_t)(b * 256 + tid) * 17;
#pragma unroll
    for (int cls = 0; cls < 17; ++cls) op[cls] = acc[cls];
}

extern "C" void kernel_launch(void* const* d_in, const int* in_sizes, int n_in,
                              void* d_out, int out_size, void* d_ws, size_t ws_size,
                              hipStream_t stream) {
    (void)in_sizes; (void)n_in; (void)out_size; (void)ws_size;
    const int*   edges = (const int*)d_in[0];
    const int*   q     = (const int*)d_in[1];
    const float* emb   = (const float*)d_in[2];
    const float* oemb  = (const float*)d_in[3];
    const float* W1    = (const float*)d_in[4];
    const float* b1    = (const float*)d_in[5];
    const float* W2    = (const float*)d_in[6];
    const float* b2    = (const float*)d_in[7];
    const float* W3    = (const float*)d_in[8];
    const float* b3    = (const float*)d_in[9];
    const float* W4    = (const float*)d_in[10];
    const float* b4    = (const float*)d_in[11];
    const float* Wih   = (const float*)d_in[12];
    const float* Whh   = (const float*)d_in[13];
    float* out = (float*)d_out;

    // ---- workspace layout (bytes, 256-aligned) ----
    char* wsp = (char*)d_ws;
    size_t off = 0;
    auto alloc = [&](size_t bytes) { void* p = wsp + off; off = (off + bytes + 255) & ~(size_t)255; return p; };
    u16*   z4     = (u16*)  alloc((size_t)NE * H * 2);              // 33.6MB (one type)
    u16*   P      = (u16*)  alloc((size_t)NCELL * 1152 * 2);        // 37.7MB
    float* gates  = (float*)P;                                      // alias (P dead then)
    float* rnn_h  = (float*)alloc((size_t)NCELL * H * 4);
    float* cst    = (float*)alloc((size_t)NCELL * H * 4);
    u16*   Ps0    = (u16*)  alloc((size_t)NCLU * H * 2);
    float* avg    = (float*)alloc((size_t)64 * H * 4);
    size_t aplane = (size_t)NCELL * 896;
    u16*   Ap     = (u16*)  alloc(aplane * 2 * 2);                  // 58.7MB
    u16*   WF     = (u16*)  alloc((size_t)983040 * 2);
    size_t bwpl   = (size_t)512 * 896;
    u16*   Bw     = (u16*)  alloc(bwpl * 2 * 2);
    size_t bppl   = (size_t)1152 * 128;
    u16*   Bp     = (u16*)  alloc(bppl * 2 * 2);
    u32*   cnt    = (u32*)  alloc((size_t)NT * NCELL * 4);
    u32*   cursor = (u32*)  alloc((size_t)NT * NCELL * 4);
    int*   perm   = (int*)  alloc((size_t)NT * NE * 4);

    // ---- one-time prep ----
    k_avg<<<64, 128, 0, stream>>>(emb, avg);
    k_init<<<1024, 256, 0, stream>>>(q, emb, avg, Ap, aplane, rnn_h, cst);
    k_prepw<<<240, 256, 0, stream>>>(W2, W3, W4, WF);
    {
        dim3 g(32, 7);
        k_packBw<<<g, 256, 0, stream>>>(Wih, Whh, Bw, bwpl);
    }
    k_packBp<<<72, 256, 0, stream>>>(W1, Bp, bppl);
    {
        dim3 g0(17, 2);
        k_gemm32<<<g0, 256, 0, stream>>>(emb, H, W1, H, Ps0, H, H);
    }
    // dst counting-sort of each edge type
    k_zerocnt<<<NT * NCELL / 256, 256, 0, stream>>>(cnt);
    k_count<<<NT * NE / 256, 256, 0, stream>>>(edges, cnt);
    k_scan<<<NT, 256, 0, stream>>>(cnt, cursor);
    k_scatter<<<NT * NE / 256, 256, 0, stream>>>(edges, cursor, perm);

    for (int s = 0; s < SSTEPS; ++s) {
        // P = h @ Wproj (bf16 out); A-frags: kt 0:4 (cell_x) at s=0 else kt 24:28 (h)
        {
            dim3 g(128, 9);
            k_gemm_bf<<<g, 256, 0, stream>>>(Ap, aplane, (s == 0) ? 0 : 24,
                                             Bp, bppl, 4, 4, nullptr, P, 1152);
        }
        // per edge type: MLP -> sorted z4, then segment-reduce -> Ap msg frags
        for (int t = 0; t < NT; ++t) {
            k_edge<<<NE / EB, 256, 0, stream>>>(edges, perm, P, Ps0, WF,
                                                b1, b2, b3, b4, z4, t);
            k_msgreduce<<<1024, 256, 0, stream>>>(z4, cnt, cursor, Ap, aplane, t);
        }
        // gates = [cell_x, msg, h] @ [Wih; Whh]  (K = 768 at s=0, 896 else)
        {
            dim3 g(128, 4);
            k_gemm_bf<<<g, 256, 0, stream>>>(Ap, aplane, 0, Bw, bwpl, AKT,
                                             (s == 0) ? 24 : 28, gates, nullptr, G4);
        }
        k_lstm<<<1024, 256, 0, stream>>>(gates, cst, rnn_h, Ap, aplane);
        k_logits<<<64, 256, 0, stream>>>(rnn_h, oemb, out + (size_t)s * NCELL * 17);
    }
}

// Round 6
// 1744.009 us; speedup vs baseline: 1.4866x; 1.4866x over previous
//
#include <hip/hip_runtime.h>
#include <math.h>

#define H 128
#define SSTEPS 3
#define NE 131072
#define NT 5
#define NCELL 16384
#define NCLU 1088
#define G4 512
#define MSGW 640     // 5*H message block
#define AKT 28       // Apack kt count (896 K-cols / 32)
#define EB 128

typedef unsigned short u16;
typedef unsigned int u32;
typedef __attribute__((ext_vector_type(8))) short short8;
typedef __attribute__((ext_vector_type(8))) unsigned short ushort8;
typedef __attribute__((ext_vector_type(4))) float f32x4;

__device__ __forceinline__ u16 f2bf(float f) {
    unsigned int u = __float_as_uint(f);
    u += 0x7fffu + ((u >> 16) & 1u);
    return (u16)(u >> 16);
}
__device__ __forceinline__ float bf2f(u16 h) {
    return __uint_as_float(((unsigned int)h) << 16);
}

// ---------------- avg of class embeddings 1..16 per batch ----------------
__global__ __launch_bounds__(128) void k_avg(const float* __restrict__ emb,
                                             float* __restrict__ avg) {
    int b = blockIdx.x, hc = threadIdx.x;
    float s = 0.f;
#pragma unroll
    for (int r = 1; r <= 16; ++r) s += emb[(b * 17 + r) * H + hc];
    avg[b * H + hc] = s * (1.0f / 16.0f);
}

// ---------------- init: cell_x -> Apack kt 0:4 (hi/lo); zero rnn_h, cst ----------------
__global__ __launch_bounds__(256) void k_init(const int* __restrict__ q,
                                              const float* __restrict__ emb,
                                              const float* __restrict__ avg,
                                              u16* __restrict__ Ap, size_t aplane,
                                              float* __restrict__ rnn_h,
                                              float* __restrict__ cst) {
    __shared__ float sx[16][132];
    int mtile = blockIdx.x, tid = threadIdx.x;
#pragma unroll
    for (int e = 0; e < 8; ++e) {
        int idx = e * 256 + tid;
        int row = idx >> 7, c = idx & 127;
        int grow = mtile * 16 + row;
        int b = grow >> 8;
        int qi = q[grow];
        const float* src = (qi == 0) ? (avg + b * H) : (emb + (b * 17 + qi) * H);
        float v = src[c];
        sx[row][c] = v;
        rnn_h[(size_t)grow * H + c] = 0.f;
        cst[(size_t)grow * H + c] = 0.f;
    }
    __syncthreads();
    int kt = tid >> 6, lane = tid & 63;
    int row = lane & 15, c0 = kt * 32 + ((lane >> 4) << 3);
    ushort8 hh, ll;
#pragma unroll
    for (int i = 0; i < 8; ++i) {
        float x = sx[row][c0 + i];
        u16 h = f2bf(x);
        hh[i] = h;
        ll[i] = f2bf(x - bf2f(h));
    }
    size_t fo = ((size_t)(mtile * AKT + kt) * 64 + lane) * 8;
    *reinterpret_cast<ushort8*>(Ap + fo) = hh;
    *reinterpret_cast<ushort8*>(Ap + aplane + fo) = ll;
}

// ---------------- zero msg buffer ----------------
__global__ __launch_bounds__(256) void k_zeromsg(float* __restrict__ msg) {
    int idx = blockIdx.x * 256 + threadIdx.x;
    reinterpret_cast<float4*>(msg)[idx] = make_float4(0.f, 0.f, 0.f, 0.f);
}

// ---------------- edge dst counting sort: zero, count, scan, scatter ----------------
__global__ __launch_bounds__(256) void k_zerocnt(u32* __restrict__ cnt) {
    cnt[blockIdx.x * 256 + threadIdx.x] = 0;
}
__global__ __launch_bounds__(256) void k_count(const int* __restrict__ edges,
                                               u32* __restrict__ cnt) {
    int gid = blockIdx.x * 256 + threadIdx.x;     // NT*NE
    int t = gid >> 17, e = gid & (NE - 1);
    int dst = edges[(t * 2 + 1) * NE + e];
    atomicAdd(&cnt[t * NCELL + dst], 1u);
}
__global__ __launch_bounds__(256) void k_scan(const u32* __restrict__ cnt,
                                              u32* __restrict__ cursor) {
    __shared__ u32 ls[256];
    int t = blockIdx.x, tid = threadIdx.x;
    const u32* c = cnt + t * NCELL;
    u32 vals[64];
    u32 s = 0;
    int base = tid * 64;
#pragma unroll
    for (int i = 0; i < 64; ++i) { vals[i] = c[base + i]; s += vals[i]; }
    ls[tid] = s;
    __syncthreads();
    for (int d = 1; d < 256; d <<= 1) {
        u32 v = (tid >= d) ? ls[tid - d] : 0;
        __syncthreads();
        ls[tid] += v;
        __syncthreads();
    }
    u32 run = ls[tid] - s;   // exclusive prefix for this chunk
#pragma unroll
    for (int i = 0; i < 64; ++i) {
        cursor[t * NCELL + base + i] = run;
        run += vals[i];
    }
}
__global__ __launch_bounds__(256) void k_scatter(const int* __restrict__ edges,
                                                 u32* __restrict__ cursor,
                                                 int* __restrict__ perm) {
    int gid = blockIdx.x * 256 + threadIdx.x;     // NT*NE
    int t = gid >> 17, e = gid & (NE - 1);
    int dst = edges[(t * 2 + 1) * NE + e];
    u32 slot = atomicAdd(&cursor[t * NCELL + dst], 1u);
    perm[t * NE + slot] = e;
}

// ---------------- fp32 GEMM -> bf16 out (Ps0 only; tiny) ----------------
__global__ __launch_bounds__(256) void k_gemm32(const float* __restrict__ A, int lda,
                                                const float* __restrict__ B, int ldb,
                                                u16* __restrict__ C, int ldc, int K) {
    __shared__ float As[64][33];
    __shared__ float Bs[32][64];
    int tid = threadIdx.x;
    int ty = tid >> 4, tx = tid & 15;
    int rbase = blockIdx.x * 64, cbase = blockIdx.y * 64;
    float acc[4][4] = {};
    for (int k0 = 0; k0 < K; k0 += 32) {
        __syncthreads();
#pragma unroll
        for (int i = 0; i < 8; ++i) {
            int id = tid + i * 256;
            int r = id >> 5, c = id & 31;
            As[r][c] = A[(size_t)(rbase + r) * lda + k0 + c];
        }
#pragma unroll
        for (int i = 0; i < 8; ++i) {
            int id = tid + i * 256;
            int r = id >> 6, c = id & 63;
            Bs[r][c] = B[(size_t)(k0 + r) * ldb + cbase + c];
        }
        __syncthreads();
#pragma unroll 8
        for (int kk = 0; kk < 32; ++kk) {
            float a[4], bv[4];
#pragma unroll
            for (int i = 0; i < 4; ++i) a[i] = As[ty * 4 + i][kk];
#pragma unroll
            for (int j = 0; j < 4; ++j) bv[j] = Bs[kk][tx * 4 + j];
#pragma unroll
            for (int i = 0; i < 4; ++i)
#pragma unroll
                for (int j = 0; j < 4; ++j) acc[i][j] = fmaf(a[i], bv[j], acc[i][j]);
        }
    }
#pragma unroll
    for (int i = 0; i < 4; ++i)
#pragma unroll
        for (int j = 0; j < 4; ++j)
            C[(size_t)(rbase + ty * 4 + i) * ldc + cbase + tx * 4 + j] = f2bf(acc[i][j]);
}

// ---------------- W2/W3/W4 -> fragment-packed bf16 hi/lo ----------------
__global__ __launch_bounds__(256) void k_prepw(const float* __restrict__ W2,
                                               const float* __restrict__ W3,
                                               const float* __restrict__ W4,
                                               u16* __restrict__ WF) {
    int bid = blockIdx.x;                  // 240 = 5*3*2*8
    int t = bid / 48;
    int l = (bid / 16) % 3;
    int p = (bid / 8) % 2;
    int nt = bid % 8;
    int tid = threadIdx.x;
    int ks = tid >> 6, lane = tid & 63;
    const float* W = (l == 0 ? W2 : l == 1 ? W3 : W4) + t * 16384;
    int n = nt * 16 + (lane & 15);
    int kb = ks * 32 + (lane >> 4) * 8;
    ushort8 o;
#pragma unroll
    for (int i = 0; i < 8; ++i) {
        float w = W[(size_t)(kb + i) * H + n];
        u16 h = f2bf(w);
        o[i] = (p == 0) ? h : f2bf(w - bf2f(h));
    }
    size_t base = ((size_t)((((t * 3 + l) * 2 + p) * 8 + nt) * 4 + ks) * 64 + lane) * 8;
    *reinterpret_cast<ushort8*>(WF + base) = o;
}

// ---------------- pack [Wih;Whh] -> B-frags hi/lo ----------------
__global__ __launch_bounds__(256) void k_packBw(const float* __restrict__ Wih,
                                                const float* __restrict__ Whh,
                                                u16* __restrict__ Bw, size_t bplane) {
    int nt = blockIdx.x;                           // 32
    int kt = blockIdx.y * 4 + (threadIdx.x >> 6);  // grid.y=7 -> 0..27
    int lane = threadIdx.x & 63;
    int n = nt * 16 + (lane & 15);
    int k0 = kt * 32 + ((lane >> 4) << 3);
    ushort8 hh, ll;
#pragma unroll
    for (int i = 0; i < 8; ++i) {
        int k = k0 + i;
        float wv = (k < 768) ? Wih[(size_t)k * G4 + n] : Whh[(size_t)(k - 768) * G4 + n];
        u16 h = f2bf(wv);
        hh[i] = h;
        ll[i] = f2bf(wv - bf2f(h));
    }
    size_t fo = ((size_t)(nt * AKT + kt) * 64 + lane) * 8;
    *reinterpret_cast<ushort8*>(Bw + fo) = hh;
    *reinterpret_cast<ushort8*>(Bw + bplane + fo) = ll;
}

// ---------------- pack projection weights (from W1) -> B-frags hi/lo ----------------
__global__ __launch_bounds__(256) void k_packBp(const float* __restrict__ W1,
                                                u16* __restrict__ Bp, size_t bplane) {
    int nt = blockIdx.x;               // 72
    int kt = threadIdx.x >> 6;         // 0..3
    int lane = threadIdx.x & 63;
    int n = nt * 16 + (lane & 15);
    int k0 = kt * 32 + ((lane >> 4) << 3);
    int t, roff, j;
    if (n < 640) { t = n >> 7; j = n & 127; roff = 128; }
    else { int m = n - 640; t = (m >> 7) + 1; j = m & 127; roff = 0; }
    ushort8 hh, ll;
#pragma unroll
    for (int i = 0; i < 8; ++i) {
        float wv = W1[((size_t)t * 256 + roff + k0 + i) * H + j];
        u16 h = f2bf(wv);
        hh[i] = h;
        ll[i] = f2bf(wv - bf2f(h));
    }
    size_t fo = ((size_t)(nt * 4 + kt) * 64 + lane) * 8;
    *reinterpret_cast<ushort8*>(Bp + fo) = hh;
    *reinterpret_cast<ushort8*>(Bp + bplane + fo) = ll;
}

// ---------------- pack msg fp32 -> Apack kt 4:24 hi/lo ----------------
__global__ __launch_bounds__(256) void k_packmsg(const float* __restrict__ msg,
                                                 u16* __restrict__ Ap, size_t aplane) {
    int mtile = blockIdx.x;
    int ktl = blockIdx.y * 4 + (threadIdx.x >> 6);   // 0..19
    int lane = threadIdx.x & 63;
    int row = mtile * 16 + (lane & 15);
    int c0 = ktl * 32 + ((lane >> 4) << 3);
    const float* src = msg + (size_t)row * MSGW + c0;
    ushort8 hh, ll;
#pragma unroll
    for (int i = 0; i < 8; ++i) {
        float x = src[i];
        u16 h = f2bf(x);
        hh[i] = h;
        ll[i] = f2bf(x - bf2f(h));
    }
    size_t fo = ((size_t)(mtile * AKT + 4 + ktl) * 64 + lane) * 8;
    *reinterpret_cast<ushort8*>(Ap + fo) = hh;
    *reinterpret_cast<ushort8*>(Ap + aplane + fo) = ll;
}

// ---------------- MFMA GEMM, 3-term split bf16, frag inputs, no LDS ----------------
__global__ __launch_bounds__(256) void k_gemm_bf(const u16* __restrict__ Ap, size_t aplane,
                                                 int aktbase,
                                                 const u16* __restrict__ Bp, size_t bplane,
                                                 int bKT, int nkt,
                                                 float* __restrict__ Cf, u16* __restrict__ Ch,
                                                 int ldc) {
    int tid = threadIdx.x;
    int w = tid >> 6, lane = tid & 63;
    int wr = w >> 1, wc = w & 1;
    int mtb = blockIdx.x * 8 + wr * 4;
    int ntb = blockIdx.y * 8 + wc * 4;
    f32x4 acc[4][4] = {};
    for (int kk = 0; kk < nkt; ++kk) {
        short8 Ah[4], Al[4], Bh[4], Bl[4];
#pragma unroll
        for (int m = 0; m < 4; ++m) {
            size_t fo = ((size_t)((mtb + m) * AKT + aktbase + kk) * 64 + lane) * 8;
            Ah[m] = *reinterpret_cast<const short8*>(Ap + fo);
            Al[m] = *reinterpret_cast<const short8*>(Ap + aplane + fo);
        }
#pragma unroll
        for (int n = 0; n < 4; ++n) {
            size_t fo = ((size_t)((ntb + n) * bKT + kk) * 64 + lane) * 8;
            Bh[n] = *reinterpret_cast<const short8*>(Bp + fo);
            Bl[n] = *reinterpret_cast<const short8*>(Bp + bplane + fo);
        }
#pragma unroll
        for (int m = 0; m < 4; ++m)
#pragma unroll
            for (int n = 0; n < 4; ++n) {
                acc[m][n] = __builtin_amdgcn_mfma_f32_16x16x32_bf16(Ah[m], Bh[n], acc[m][n], 0, 0, 0);
                acc[m][n] = __builtin_amdgcn_mfma_f32_16x16x32_bf16(Ah[m], Bl[n], acc[m][n], 0, 0, 0);
                acc[m][n] = __builtin_amdgcn_mfma_f32_16x16x32_bf16(Al[m], Bh[n], acc[m][n], 0, 0, 0);
            }
    }
#pragma unroll
    for (int m = 0; m < 4; ++m)
#pragma unroll
        for (int r = 0; r < 4; ++r) {
            int row = (mtb + m) * 16 + (lane >> 4) * 4 + r;
#pragma unroll
            for (int n = 0; n < 4; ++n) {
                int col = (ntb + n) * 16 + (lane & 15);
                float v = acc[m][n][r];
                if (Ch) Ch[(size_t)row * ldc + col] = f2bf(v);
                else Cf[(size_t)row * ldc + col] = v;
            }
        }
}

// ---------------- fused per-edge MLP: sorted edges; block-local seg-reduce; ----------------
// ---------------- plain stores for interior dsts, atomics only at block boundaries --------
__global__ __launch_bounds__(256, 3) void k_edge(const int* __restrict__ edges,
                                                 const int* __restrict__ perm,
                                                 const u16* __restrict__ P,
                                                 const u16* __restrict__ Ps0,
                                                 const u16* __restrict__ WF,
                                                 const float* __restrict__ bb1,
                                                 const float* __restrict__ bb2,
                                                 const float* __restrict__ bb3,
                                                 const float* __restrict__ bb4,
                                                 float* __restrict__ msg) {
    __shared__ u16 zh[EB * H];    // 32KB, 16B-chunk XOR swizzle
    __shared__ int sdst[EB];
    int tid = threadIdx.x;
    int w = tid >> 6, lane = tid & 63;
    int bid = blockIdx.x;
    int t = bid >> 10, tile = bid & 1023;
    int ebase = tile * EB;

    // ---- layer 1 (edges in dst-sorted order via perm) ----
    {
        int row = tid >> 1, half = tid & 1;
        int eo = perm[t * NE + ebase + row];
        int sn = edges[(t * 2) * NE + eo];
        int dn = edges[(t * 2 + 1) * NE + eo];
        if (half == 0) sdst[row] = dn;
        const u16* ps = (t == 0) ? Ps0 + (size_t)sn * H
                                 : P + (size_t)sn * 1152 + 640 + (t - 1) * H;
        const u16* pd = P + (size_t)dn * 1152 + t * H;
        const float* bb = bb1 + t * H;
#pragma unroll
        for (int cc = 0; cc < 8; ++cc) {
            int c8 = half * 8 + cc;
            ushort8 a = *reinterpret_cast<const ushort8*>(ps + c8 * 8);
            ushort8 d = *reinterpret_cast<const ushort8*>(pd + c8 * 8);
            float4 b0 = *reinterpret_cast<const float4*>(bb + c8 * 8);
            float4 b1v = *reinterpret_cast<const float4*>(bb + c8 * 8 + 4);
            float bv[8] = {b0.x, b0.y, b0.z, b0.w, b1v.x, b1v.y, b1v.z, b1v.w};
            ushort8 hh;
#pragma unroll
            for (int i = 0; i < 8; ++i)
                hh[i] = f2bf(fmaxf(bf2f(a[i]) + bf2f(d[i]) + bv[i], 0.f));
            *reinterpret_cast<ushort8*>(&zh[row * H + ((c8 ^ (row & 7)) << 3)]) = hh;
        }
    }
    __syncthreads();

    const u16* wfbase = WF + (size_t)(t * 3) * 32768;
    f32x4 acc[8][2];
    short8 Bh[2][4], Bl[2][4];

    // ---- layers 2,3 (normal orientation: C[row=edge][col=feature]) ----
#pragma unroll 1
    for (int l = 0; l < 2; ++l) {
        const u16* wl = wfbase + l * 32768;
#pragma unroll
        for (int ng = 0; ng < 2; ++ng)
#pragma unroll
            for (int ks = 0; ks < 4; ++ks) {
                int nt = 2 * w + ng;
                Bh[ng][ks] = *reinterpret_cast<const short8*>(wl + ((nt * 4 + ks) * 64 + lane) * 8);
                Bl[ng][ks] = *reinterpret_cast<const short8*>(wl + ((32 + nt * 4 + ks) * 64 + lane) * 8);
            }
#pragma unroll
        for (int mt = 0; mt < 8; ++mt)
#pragma unroll
            for (int ng = 0; ng < 2; ++ng)
                acc[mt][ng] = (f32x4){0.f, 0.f, 0.f, 0.f};
#pragma unroll
        for (int mt = 0; mt < 8; ++mt) {
            short8 Ah[4];
            int rr = mt * 16 + (lane & 15);
#pragma unroll
            for (int ks = 0; ks < 4; ++ks) {
                int ch = ks * 4 + (lane >> 4);
                Ah[ks] = *reinterpret_cast<const short8*>(&zh[rr * H + ((ch ^ (rr & 7)) << 3)]);
            }
#pragma unroll
            for (int ng = 0; ng < 2; ++ng)
#pragma unroll
                for (int ks = 0; ks < 4; ++ks) {
                    acc[mt][ng] = __builtin_amdgcn_mfma_f32_16x16x32_bf16(Ah[ks], Bh[ng][ks], acc[mt][ng], 0, 0, 0);
                    acc[mt][ng] = __builtin_amdgcn_mfma_f32_16x16x32_bf16(Ah[ks], Bl[ng][ks], acc[mt][ng], 0, 0, 0);
                }
        }
        __syncthreads();   // all reads of zh done
        const float* bb = (l == 0 ? bb2 : bb3) + t * H;
        float bi[2];
#pragma unroll
        for (int ng = 0; ng < 2; ++ng) bi[ng] = bb[(2 * w + ng) * 16 + (lane & 15)];
#pragma unroll
        for (int mt = 0; mt < 8; ++mt)
#pragma unroll
            for (int ng = 0; ng < 2; ++ng) {
                int col = (2 * w + ng) * 16 + (lane & 15);
#pragma unroll
                for (int r = 0; r < 4; ++r) {
                    int rr = mt * 16 + (lane >> 4) * 4 + r;
                    float x = fmaxf(acc[mt][ng][r] + bi[ng], 0.f);
                    zh[rr * H + (((col >> 3) ^ (rr & 7)) << 3) + (col & 7)] = f2bf(x);
                }
            }
        __syncthreads();   // writes visible
    }

    // ---- layer 4: transposed (C[feature][edge]) + block seg-reduce ----
    {
        const u16* wl = wfbase + 2 * 32768;
#pragma unroll
        for (int fg = 0; fg < 2; ++fg)
#pragma unroll
            for (int ks = 0; ks < 4; ++ks) {
                int nt = 2 * w + fg;
                Bh[fg][ks] = *reinterpret_cast<const short8*>(wl + ((nt * 4 + ks) * 64 + lane) * 8);
                Bl[fg][ks] = *reinterpret_cast<const short8*>(wl + ((32 + nt * 4 + ks) * 64 + lane) * 8);
            }
#pragma unroll
        for (int et = 0; et < 8; ++et)
#pragma unroll
            for (int fg = 0; fg < 2; ++fg)
                acc[et][fg] = (f32x4){0.f, 0.f, 0.f, 0.f};
#pragma unroll
        for (int et = 0; et < 8; ++et) {
            short8 zf[4];
            int rr = et * 16 + (lane & 15);
#pragma unroll
            for (int ks = 0; ks < 4; ++ks) {
                int ch = ks * 4 + (lane >> 4);
                zf[ks] = *reinterpret_cast<const short8*>(&zh[rr * H + ((ch ^ (rr & 7)) << 3)]);
            }
#pragma unroll
            for (int fg = 0; fg < 2; ++fg)
#pragma unroll
                for (int ks = 0; ks < 4; ++ks) {
                    acc[et][fg] = __builtin_amdgcn_mfma_f32_16x16x32_bf16(Bh[fg][ks], zf[ks], acc[et][fg], 0, 0, 0);
                    acc[et][fg] = __builtin_amdgcn_mfma_f32_16x16x32_bf16(Bl[fg][ks], zf[ks], acc[et][fg], 0, 0, 0);
                }
        }
        const float* bb = bb4 + t * H;
        float bi[2][4];
#pragma unroll
        for (int fg = 0; fg < 2; ++fg)
#pragma unroll
            for (int r = 0; r < 4; ++r)
                bi[fg][r] = bb[(2 * w + fg) * 16 + (lane >> 4) * 4 + r];

        int pos = lane & 15;
        int lgbase = lane & 48;               // shfl base of this 16-lane group
        int d_first = sdst[0], d_last = sdst[EB - 1];
        int cd = -1;                          // carry dst from previous et group
        f32x4 cs0 = (f32x4){0.f, 0.f, 0.f, 0.f}, cs1 = cs0;
#pragma unroll 1
        for (int et = 0; et < 8; ++et) {
            int idx = et * 16 + pos;
            int d = sdst[idx];
            f32x4 s0 = acc[et][0], s1 = acc[et][1];
#pragma unroll
            for (int r = 0; r < 4; ++r) { s0[r] += bi[0][r]; s1[r] += bi[1][r]; }
            // in-group segmented inclusive scan (dsts sorted ascending)
#pragma unroll
            for (int dist = 1; dist < 16; dist <<= 1) {
                int pd_ = __shfl_up(d, dist, 64);
                f32x4 t0, t1;
#pragma unroll
                for (int r = 0; r < 4; ++r) {
                    t0[r] = __shfl_up(s0[r], dist, 64);
                    t1[r] = __shfl_up(s1[r], dist, 64);
                }
                if ((pos >= dist) && (pd_ == d)) {
#pragma unroll
                    for (int r = 0; r < 4; ++r) { s0[r] += t0[r]; s1[r] += t1[r]; }
                }
            }
            // fold in carry: sorted => run containing position 0 is exactly {d == d0}
            int d0 = __shfl(d, lgbase, 64);
            if (d == d0 && cd == d0) {
#pragma unroll
                for (int r = 0; r < 4; ++r) { s0[r] += cs0[r]; s1[r] += cs1[r]; }
            }
            // tail = last edge of its run within this block
            int nd = (idx < EB - 1) ? sdst[idx + 1] : -2;
            if (nd != d) {
                bool bdry = (d == d_first) || (d == d_last);
                float* m0 = msg + (size_t)d * MSGW + t * H + (2 * w) * 16 + (lane >> 4) * 4;
                float* m1 = m0 + 16;
                if (bdry) {
#pragma unroll
                    for (int r = 0; r < 4; ++r) {
                        atomicAdd(m0 + r, s0[r]);
                        atomicAdd(m1 + r, s1[r]);
                    }
                } else {
                    *reinterpret_cast<float4*>(m0) = make_float4(s0[0], s0[1], s0[2], s0[3]);
                    *reinterpret_cast<float4*>(m1) = make_float4(s1[0], s1[1], s1[2], s1[3]);
                }
            }
            // carry = inclusive sum at position 15 of this group
            cd = __shfl(d, lgbase + 15, 64);
#pragma unroll
            for (int r = 0; r < 4; ++r) {
                cs0[r] = __shfl(s0[r], lgbase + 15, 64);
                cs1[r] = __shfl(s1[r], lgbase + 15, 64);
            }
        }
    }
}

// ---------------- LSTM pointwise + h frag pack (kt 24:28) ----------------
__global__ __launch_bounds__(256) void k_lstm(const float* __restrict__ gates,
                                              float* __restrict__ cst,
                                              float* __restrict__ rnn_h,
                                              u16* __restrict__ Ap, size_t aplane) {
    __shared__ float sh[16][132];
    int mtile = blockIdx.x, tid = threadIdx.x;
#pragma unroll
    for (int e = 0; e < 8; ++e) {
        int idx = e * 256 + tid;
        int row = idx >> 7, c = idx & 127;
        int grow = mtile * 16 + row;
        const float* g = gates + (size_t)grow * G4;
        float ig = g[c], fg = g[128 + c], gg = g[256 + c], og = g[384 + c];
        size_t ci = (size_t)grow * H + c;
        float c_old = cst[ci];
        float i_s = 1.f / (1.f + expf(-ig));
        float f_s = 1.f / (1.f + expf(-fg));
        float o_s = 1.f / (1.f + expf(-og));
        float c_new = f_s * c_old + i_s * tanhf(gg);
        float h_new = o_s * tanhf(c_new);
        cst[ci] = c_new;
        rnn_h[ci] = h_new;
        sh[row][c] = h_new;
    }
    __syncthreads();
    int kt = tid >> 6, lane = tid & 63;
    int row = lane & 15, c0 = kt * 32 + ((lane >> 4) << 3);
    ushort8 hh, ll;
#pragma unroll
    for (int i = 0; i < 8; ++i) {
        float x = sh[row][c0 + i];
        u16 h = f2bf(x);
        hh[i] = h;
        ll[i] = f2bf(x - bf2f(h));
    }
    size_t fo = ((size_t)(mtile * AKT + 24 + kt) * 64 + lane) * 8;
    *reinterpret_cast<ushort8*>(Ap + fo) = hh;
    *reinterpret_cast<ushort8*>(Ap + aplane + fo) = ll;
}

// ---------------- logits ----------------
__global__ __launch_bounds__(256) void k_logits(const float* __restrict__ h,
                                                const float* __restrict__ oemb,
                                                float* __restrict__ out) {
    __shared__ float oe[17][129];
    int b = blockIdx.x, tid = threadIdx.x;
    for (int id = tid; id < 17 * 128; id += 256) {
        int r = id >> 7, c = id & 127;
        oe[r][c] = oemb[(b * 17 + r) * H + c];
    }
    __syncthreads();
    const float* hr = h + (size_t)(b * 256 + tid) * H;
    float acc[17] = {};
    for (int v = 0; v < 32; ++v) {
        float4 hv = reinterpret_cast<const float4*>(hr)[v];
#pragma unroll
        for (int cls = 0; cls < 17; ++cls) {
            acc[cls] = fmaf(hv.x, oe[cls][v * 4 + 0],
                       fmaf(hv.y, oe[cls][v * 4 + 1],
                       fmaf(hv.z, oe[cls][v * 4 + 2],
                       fmaf(hv.w, oe[cls][v * 4 + 3], acc[cls]))));
        }
    }
    float* op = out + (size_t)(b * 256 + tid) * 17;
#pragma unroll
    for (int cls = 0; cls < 17; ++cls) op[cls] = acc[cls];
}

extern "C" void kernel_launch(void* const* d_in, const int* in_sizes, int n_in,
                              void* d_out, int out_size, void* d_ws, size_t ws_size,
                              hipStream_t stream) {
    (void)in_sizes; (void)n_in; (void)out_size; (void)ws_size;
    const int*   edges = (const int*)d_in[0];
    const int*   q     = (const int*)d_in[1];
    const float* emb   = (const float*)d_in[2];
    const float* oemb  = (const float*)d_in[3];
    const float* W1    = (const float*)d_in[4];
    const float* b1    = (const float*)d_in[5];
    const float* W2    = (const float*)d_in[6];
    const float* b2    = (const float*)d_in[7];
    const float* W3    = (const float*)d_in[8];
    const float* b3    = (const float*)d_in[9];
    const float* W4    = (const float*)d_in[10];
    const float* b4    = (const float*)d_in[11];
    const float* Wih   = (const float*)d_in[12];
    const float* Whh   = (const float*)d_in[13];
    float* out = (float*)d_out;

    // ---- workspace layout (bytes, 256-aligned) ----
    char* wsp = (char*)d_ws;
    size_t off = 0;
    auto alloc = [&](size_t bytes) { void* p = wsp + off; off = (off + bytes + 255) & ~(size_t)255; return p; };
    float* msg    = (float*)alloc((size_t)NCELL * MSGW * 4);
    u16*   P      = (u16*)  alloc((size_t)NCELL * 1152 * 2);
    float* gates  = (float*)P;                                      // alias
    float* rnn_h  = (float*)alloc((size_t)NCELL * H * 4);
    float* cst    = (float*)alloc((size_t)NCELL * H * 4);
    u16*   Ps0    = (u16*)  alloc((size_t)NCLU * H * 2);
    float* avg    = (float*)alloc((size_t)64 * H * 4);
    size_t aplane = (size_t)NCELL * 896;
    u16*   Ap     = (u16*)  alloc(aplane * 2 * 2);
    u16*   WF     = (u16*)  alloc((size_t)983040 * 2);
    size_t bwpl   = (size_t)512 * 896;
    u16*   Bw     = (u16*)  alloc(bwpl * 2 * 2);
    size_t bppl   = (size_t)1152 * 128;
    u16*   Bp     = (u16*)  alloc(bppl * 2 * 2);
    u32*   cnt    = (u32*)  alloc((size_t)NT * NCELL * 4);
    u32*   cursor = (u32*)  alloc((size_t)NT * NCELL * 4);
    int*   perm   = (int*)  alloc((size_t)NT * NE * 4);

    // ---- one-time prep ----
    k_avg<<<64, 128, 0, stream>>>(emb, avg);
    k_init<<<1024, 256, 0, stream>>>(q, emb, avg, Ap, aplane, rnn_h, cst);
    k_prepw<<<240, 256, 0, stream>>>(W2, W3, W4, WF);
    {
        dim3 g(32, 7);
        k_packBw<<<g, 256, 0, stream>>>(Wih, Whh, Bw, bwpl);
    }
    k_packBp<<<72, 256, 0, stream>>>(W1, Bp, bppl);
    {
        dim3 g0(17, 2);
        k_gemm32<<<g0, 256, 0, stream>>>(emb, H, W1, H, Ps0, H, H);
    }
    // dst counting-sort of each edge type
    k_zerocnt<<<NT * NCELL / 256, 256, 0, stream>>>(cnt);
    k_count<<<NT * NE / 256, 256, 0, stream>>>(edges, cnt);
    k_scan<<<NT, 256, 0, stream>>>(cnt, cursor);
    k_scatter<<<NT * NE / 256, 256, 0, stream>>>(edges, cursor, perm);

    for (int s = 0; s < SSTEPS; ++s) {
        k_zeromsg<<<NCELL * MSGW / 4 / 256, 256, 0, stream>>>(msg);
        {
            dim3 g(128, 9);
            k_gemm_bf<<<g, 256, 0, stream>>>(Ap, aplane, (s == 0) ? 0 : 24,
                                             Bp, bppl, 4, 4, nullptr, P, 1152);
        }
        k_edge<<<NT * (NE / EB), 256, 0, stream>>>(edges, perm, P, Ps0, WF,
                                                   b1, b2, b3, b4, msg);
        {
            dim3 g(1024, 5);
            k_packmsg<<<g, 256, 0, stream>>>(msg, Ap, aplane);
        }
        {
            dim3 g(128, 4);
            k_gemm_bf<<<g, 256, 0, stream>>>(Ap, aplane, 0, Bw, bwpl, AKT,
                                             (s == 0) ? 24 : 28, gates, nullptr, G4);
        }
        k_lstm<<<1024, 256, 0, stream>>>(gates, cst, rnn_h, Ap, aplane);
        k_logits<<<64, 256, 0, stream>>>(rnn_h, oemb, out + (size_t)s * NCELL * 17);
    }
}

// Round 7
// 1686.609 us; speedup vs baseline: 1.5372x; 1.0340x over previous
//
#include <hip/hip_runtime.h>
#include <math.h>

#define H 128
#define SSTEPS 3
#define NE 131072
#define NT 5
#define NCELL 16384
#define NCLU 1088
#define G4 512
#define MSGW 640     // 5*H message block
#define AKT 28       // Apack kt count (896 K-cols / 32)
#define EB 128

typedef unsigned short u16;
typedef unsigned int u32;
typedef __attribute__((ext_vector_type(8))) short short8;
typedef __attribute__((ext_vector_type(8))) unsigned short ushort8;
typedef __attribute__((ext_vector_type(4))) float f32x4;

__device__ __forceinline__ u16 f2bf(float f) {
    unsigned int u = __float_as_uint(f);
    u += 0x7fffu + ((u >> 16) & 1u);
    return (u16)(u >> 16);
}
__device__ __forceinline__ float bf2f(u16 h) {
    return __uint_as_float(((unsigned int)h) << 16);
}

// ---------------- avg of class embeddings 1..16 per batch ----------------
__global__ __launch_bounds__(128) void k_avg(const float* __restrict__ emb,
                                             float* __restrict__ avg) {
    int b = blockIdx.x, hc = threadIdx.x;
    float s = 0.f;
#pragma unroll
    for (int r = 1; r <= 16; ++r) s += emb[(b * 17 + r) * H + hc];
    avg[b * H + hc] = s * (1.0f / 16.0f);
}

// ---------------- init: cell_x -> Apack kt 0:4 (hi/lo); zero rnn_h, cst ----------------
__global__ __launch_bounds__(256) void k_init(const int* __restrict__ q,
                                              const float* __restrict__ emb,
                                              const float* __restrict__ avg,
                                              u16* __restrict__ Ap, size_t aplane,
                                              float* __restrict__ rnn_h,
                                              float* __restrict__ cst) {
    __shared__ float sx[16][132];
    int mtile = blockIdx.x, tid = threadIdx.x;
#pragma unroll
    for (int e = 0; e < 8; ++e) {
        int idx = e * 256 + tid;
        int row = idx >> 7, c = idx & 127;
        int grow = mtile * 16 + row;
        int b = grow >> 8;
        int qi = q[grow];
        const float* src = (qi == 0) ? (avg + b * H) : (emb + (b * 17 + qi) * H);
        float v = src[c];
        sx[row][c] = v;
        rnn_h[(size_t)grow * H + c] = 0.f;
        cst[(size_t)grow * H + c] = 0.f;
    }
    __syncthreads();
    int kt = tid >> 6, lane = tid & 63;
    int row = lane & 15, c0 = kt * 32 + ((lane >> 4) << 3);
    ushort8 hh, ll;
#pragma unroll
    for (int i = 0; i < 8; ++i) {
        float x = sx[row][c0 + i];
        u16 h = f2bf(x);
        hh[i] = h;
        ll[i] = f2bf(x - bf2f(h));
    }
    size_t fo = ((size_t)(mtile * AKT + kt) * 64 + lane) * 8;
    *reinterpret_cast<ushort8*>(Ap + fo) = hh;
    *reinterpret_cast<ushort8*>(Ap + aplane + fo) = ll;
}

// ---------------- zero msg buffer ----------------
__global__ __launch_bounds__(256) void k_zeromsg(float* __restrict__ msg) {
    int idx = blockIdx.x * 256 + threadIdx.x;
    reinterpret_cast<float4*>(msg)[idx] = make_float4(0.f, 0.f, 0.f, 0.f);
}

// ---------------- fp32 GEMM -> bf16 out (Ps0 only; tiny) ----------------
__global__ __launch_bounds__(256) void k_gemm32(const float* __restrict__ A, int lda,
                                                const float* __restrict__ B, int ldb,
                                                u16* __restrict__ C, int ldc, int K) {
    __shared__ float As[64][33];
    __shared__ float Bs[32][64];
    int tid = threadIdx.x;
    int ty = tid >> 4, tx = tid & 15;
    int rbase = blockIdx.x * 64, cbase = blockIdx.y * 64;
    float acc[4][4] = {};
    for (int k0 = 0; k0 < K; k0 += 32) {
        __syncthreads();
#pragma unroll
        for (int i = 0; i < 8; ++i) {
            int id = tid + i * 256;
            int r = id >> 5, c = id & 31;
            As[r][c] = A[(size_t)(rbase + r) * lda + k0 + c];
        }
#pragma unroll
        for (int i = 0; i < 8; ++i) {
            int id = tid + i * 256;
            int r = id >> 6, c = id & 63;
            Bs[r][c] = B[(size_t)(k0 + r) * ldb + cbase + c];
        }
        __syncthreads();
#pragma unroll 8
        for (int kk = 0; kk < 32; ++kk) {
            float a[4], bv[4];
#pragma unroll
            for (int i = 0; i < 4; ++i) a[i] = As[ty * 4 + i][kk];
#pragma unroll
            for (int j = 0; j < 4; ++j) bv[j] = Bs[kk][tx * 4 + j];
#pragma unroll
            for (int i = 0; i < 4; ++i)
#pragma unroll
                for (int j = 0; j < 4; ++j) acc[i][j] = fmaf(a[i], bv[j], acc[i][j]);
        }
    }
#pragma unroll
    for (int i = 0; i < 4; ++i)
#pragma unroll
        for (int j = 0; j < 4; ++j)
            C[(size_t)(rbase + ty * 4 + i) * ldc + cbase + tx * 4 + j] = f2bf(acc[i][j]);
}

// ---------------- W2/W3/W4 -> fragment-packed bf16 hi/lo ----------------
__global__ __launch_bounds__(256) void k_prepw(const float* __restrict__ W2,
                                               const float* __restrict__ W3,
                                               const float* __restrict__ W4,
                                               u16* __restrict__ WF) {
    int bid = blockIdx.x;                  // 240 = 5*3*2*8
    int t = bid / 48;
    int l = (bid / 16) % 3;
    int p = (bid / 8) % 2;
    int nt = bid % 8;
    int tid = threadIdx.x;
    int ks = tid >> 6, lane = tid & 63;
    const float* W = (l == 0 ? W2 : l == 1 ? W3 : W4) + t * 16384;
    int n = nt * 16 + (lane & 15);
    int kb = ks * 32 + (lane >> 4) * 8;
    ushort8 o;
#pragma unroll
    for (int i = 0; i < 8; ++i) {
        float w = W[(size_t)(kb + i) * H + n];
        u16 h = f2bf(w);
        o[i] = (p == 0) ? h : f2bf(w - bf2f(h));
    }
    size_t base = ((size_t)((((t * 3 + l) * 2 + p) * 8 + nt) * 4 + ks) * 64 + lane) * 8;
    *reinterpret_cast<ushort8*>(WF + base) = o;
}

// ---------------- pack [Wih;Whh] -> B-frags hi/lo ----------------
__global__ __launch_bounds__(256) void k_packBw(const float* __restrict__ Wih,
                                                const float* __restrict__ Whh,
                                                u16* __restrict__ Bw, size_t bplane) {
    int nt = blockIdx.x;                           // 32
    int kt = blockIdx.y * 4 + (threadIdx.x >> 6);  // grid.y=7 -> 0..27
    int lane = threadIdx.x & 63;
    int n = nt * 16 + (lane & 15);
    int k0 = kt * 32 + ((lane >> 4) << 3);
    ushort8 hh, ll;
#pragma unroll
    for (int i = 0; i < 8; ++i) {
        int k = k0 + i;
        float wv = (k < 768) ? Wih[(size_t)k * G4 + n] : Whh[(size_t)(k - 768) * G4 + n];
        u16 h = f2bf(wv);
        hh[i] = h;
        ll[i] = f2bf(wv - bf2f(h));
    }
    size_t fo = ((size_t)(nt * AKT + kt) * 64 + lane) * 8;
    *reinterpret_cast<ushort8*>(Bw + fo) = hh;
    *reinterpret_cast<ushort8*>(Bw + bplane + fo) = ll;
}

// ---------------- pack projection weights (from W1) -> B-frags hi/lo ----------------
__global__ __launch_bounds__(256) void k_packBp(const float* __restrict__ W1,
                                                u16* __restrict__ Bp, size_t bplane) {
    int nt = blockIdx.x;               // 72
    int kt = threadIdx.x >> 6;         // 0..3
    int lane = threadIdx.x & 63;
    int n = nt * 16 + (lane & 15);
    int k0 = kt * 32 + ((lane >> 4) << 3);
    int t, roff, j;
    if (n < 640) { t = n >> 7; j = n & 127; roff = 128; }
    else { int m = n - 640; t = (m >> 7) + 1; j = m & 127; roff = 0; }
    ushort8 hh, ll;
#pragma unroll
    for (int i = 0; i < 8; ++i) {
        float wv = W1[((size_t)t * 256 + roff + k0 + i) * H + j];
        u16 h = f2bf(wv);
        hh[i] = h;
        ll[i] = f2bf(wv - bf2f(h));
    }
    size_t fo = ((size_t)(nt * 4 + kt) * 64 + lane) * 8;
    *reinterpret_cast<ushort8*>(Bp + fo) = hh;
    *reinterpret_cast<ushort8*>(Bp + bplane + fo) = ll;
}

// ---------------- pack msg fp32 -> Apack kt 4:24 hi/lo ----------------
__global__ __launch_bounds__(256) void k_packmsg(const float* __restrict__ msg,
                                                 u16* __restrict__ Ap, size_t aplane) {
    int mtile = blockIdx.x;
    int ktl = blockIdx.y * 4 + (threadIdx.x >> 6);   // 0..19
    int lane = threadIdx.x & 63;
    int row = mtile * 16 + (lane & 15);
    int c0 = ktl * 32 + ((lane >> 4) << 3);
    const float* src = msg + (size_t)row * MSGW + c0;
    ushort8 hh, ll;
#pragma unroll
    for (int i = 0; i < 8; ++i) {
        float x = src[i];
        u16 h = f2bf(x);
        hh[i] = h;
        ll[i] = f2bf(x - bf2f(h));
    }
    size_t fo = ((size_t)(mtile * AKT + 4 + ktl) * 64 + lane) * 8;
    *reinterpret_cast<ushort8*>(Ap + fo) = hh;
    *reinterpret_cast<ushort8*>(Ap + aplane + fo) = ll;
}

// ---------------- MFMA GEMM, 3-term split bf16, frag inputs, no LDS ----------------
__global__ __launch_bounds__(256) void k_gemm_bf(const u16* __restrict__ Ap, size_t aplane,
                                                 int aktbase,
                                                 const u16* __restrict__ Bp, size_t bplane,
                                                 int bKT, int nkt,
                                                 float* __restrict__ Cf, u16* __restrict__ Ch,
                                                 int ldc) {
    int tid = threadIdx.x;
    int w = tid >> 6, lane = tid & 63;
    int wr = w >> 1, wc = w & 1;
    int mtb = blockIdx.x * 8 + wr * 4;
    int ntb = blockIdx.y * 8 + wc * 4;
    f32x4 acc[4][4] = {};
    for (int kk = 0; kk < nkt; ++kk) {
        short8 Ah[4], Al[4], Bh[4], Bl[4];
#pragma unroll
        for (int m = 0; m < 4; ++m) {
            size_t fo = ((size_t)((mtb + m) * AKT + aktbase + kk) * 64 + lane) * 8;
            Ah[m] = *reinterpret_cast<const short8*>(Ap + fo);
            Al[m] = *reinterpret_cast<const short8*>(Ap + aplane + fo);
        }
#pragma unroll
        for (int n = 0; n < 4; ++n) {
            size_t fo = ((size_t)((ntb + n) * bKT + kk) * 64 + lane) * 8;
            Bh[n] = *reinterpret_cast<const short8*>(Bp + fo);
            Bl[n] = *reinterpret_cast<const short8*>(Bp + bplane + fo);
        }
#pragma unroll
        for (int m = 0; m < 4; ++m)
#pragma unroll
            for (int n = 0; n < 4; ++n) {
                acc[m][n] = __builtin_amdgcn_mfma_f32_16x16x32_bf16(Ah[m], Bh[n], acc[m][n], 0, 0, 0);
                acc[m][n] = __builtin_amdgcn_mfma_f32_16x16x32_bf16(Ah[m], Bl[n], acc[m][n], 0, 0, 0);
                acc[m][n] = __builtin_amdgcn_mfma_f32_16x16x32_bf16(Al[m], Bh[n], acc[m][n], 0, 0, 0);
            }
    }
#pragma unroll
    for (int m = 0; m < 4; ++m)
#pragma unroll
        for (int r = 0; r < 4; ++r) {
            int row = (mtb + m) * 16 + (lane >> 4) * 4 + r;
#pragma unroll
            for (int n = 0; n < 4; ++n) {
                int col = (ntb + n) * 16 + (lane & 15);
                float v = acc[m][n][r];
                if (Ch) Ch[(size_t)row * ldc + col] = f2bf(v);
                else Cf[(size_t)row * ldc + col] = v;
            }
        }
}

// ---------------- fused per-edge MLP: col-split waves, A-hi * (B-hi+B-lo) ----------------
// R2-proven structure + 4 blocks/CU + per-mt interleaved atomic scatter in layer 4
__global__ __launch_bounds__(256, 4) void k_edge(const int* __restrict__ edges,
                                                 const u16* __restrict__ P,
                                                 const u16* __restrict__ Ps0,
                                                 const u16* __restrict__ WF,
                                                 const float* __restrict__ bb1,
                                                 const float* __restrict__ bb2,
                                                 const float* __restrict__ bb3,
                                                 const float* __restrict__ bb4,
                                                 float* __restrict__ msg) {
    __shared__ u16 zh[EB * H];    // 32KB, 16B-chunk XOR swizzle
    __shared__ int sdst[EB];
    int tid = threadIdx.x;
    int w = tid >> 6, lane = tid & 63;
    int bid = blockIdx.x;
    int t = bid >> 10, tile = bid & 1023;
    int ebase = tile * EB;

    // ---- layer 1 ----
    {
        int row = tid >> 1, half = tid & 1;
        int e = ebase + row;
        int sn = edges[(t * 2) * NE + e];
        int dn = edges[(t * 2 + 1) * NE + e];
        if (half == 0) sdst[row] = dn;
        const u16* ps = (t == 0) ? Ps0 + (size_t)sn * H
                                 : P + (size_t)sn * 1152 + 640 + (t - 1) * H;
        const u16* pd = P + (size_t)dn * 1152 + t * H;
        const float* bb = bb1 + t * H;
#pragma unroll
        for (int cc = 0; cc < 8; ++cc) {
            int c8 = half * 8 + cc;
            ushort8 a = *reinterpret_cast<const ushort8*>(ps + c8 * 8);
            ushort8 d = *reinterpret_cast<const ushort8*>(pd + c8 * 8);
            float4 b0 = *reinterpret_cast<const float4*>(bb + c8 * 8);
            float4 b1v = *reinterpret_cast<const float4*>(bb + c8 * 8 + 4);
            float bv[8] = {b0.x, b0.y, b0.z, b0.w, b1v.x, b1v.y, b1v.z, b1v.w};
            ushort8 hh;
#pragma unroll
            for (int i = 0; i < 8; ++i)
                hh[i] = f2bf(fmaxf(bf2f(a[i]) + bf2f(d[i]) + bv[i], 0.f));
            *reinterpret_cast<ushort8*>(&zh[row * H + ((c8 ^ (row & 7)) << 3)]) = hh;
        }
    }
    __syncthreads();

    const u16* wfbase = WF + (size_t)(t * 3) * 32768;
    short8 Bh[2][4], Bl[2][4];

    // ---- layers 2,3 (C[row=edge][col=feature], zh ping-pong with barriers) ----
#pragma unroll 1
    for (int l = 0; l < 2; ++l) {
        const u16* wl = wfbase + l * 32768;
#pragma unroll
        for (int ng = 0; ng < 2; ++ng)
#pragma unroll
            for (int ks = 0; ks < 4; ++ks) {
                int nt = 2 * w + ng;
                Bh[ng][ks] = *reinterpret_cast<const short8*>(wl + ((nt * 4 + ks) * 64 + lane) * 8);
                Bl[ng][ks] = *reinterpret_cast<const short8*>(wl + ((32 + nt * 4 + ks) * 64 + lane) * 8);
            }
        f32x4 acc[8][2];
#pragma unroll
        for (int mt = 0; mt < 8; ++mt)
#pragma unroll
            for (int ng = 0; ng < 2; ++ng)
                acc[mt][ng] = (f32x4){0.f, 0.f, 0.f, 0.f};
#pragma unroll
        for (int mt = 0; mt < 8; ++mt) {
            short8 Ah[4];
            int rr = mt * 16 + (lane & 15);
#pragma unroll
            for (int ks = 0; ks < 4; ++ks) {
                int ch = ks * 4 + (lane >> 4);
                Ah[ks] = *reinterpret_cast<const short8*>(&zh[rr * H + ((ch ^ (rr & 7)) << 3)]);
            }
#pragma unroll
            for (int ng = 0; ng < 2; ++ng)
#pragma unroll
                for (int ks = 0; ks < 4; ++ks) {
                    acc[mt][ng] = __builtin_amdgcn_mfma_f32_16x16x32_bf16(Ah[ks], Bh[ng][ks], acc[mt][ng], 0, 0, 0);
                    acc[mt][ng] = __builtin_amdgcn_mfma_f32_16x16x32_bf16(Ah[ks], Bl[ng][ks], acc[mt][ng], 0, 0, 0);
                }
        }
        __syncthreads();   // all reads of zh done
        const float* bb = (l == 0 ? bb2 : bb3) + t * H;
        float bi[2];
#pragma unroll
        for (int ng = 0; ng < 2; ++ng) bi[ng] = bb[(2 * w + ng) * 16 + (lane & 15)];
#pragma unroll
        for (int mt = 0; mt < 8; ++mt)
#pragma unroll
            for (int ng = 0; ng < 2; ++ng) {
                int col = (2 * w + ng) * 16 + (lane & 15);
#pragma unroll
                for (int r = 0; r < 4; ++r) {
                    int rr = mt * 16 + (lane >> 4) * 4 + r;
                    float x = fmaxf(acc[mt][ng][r] + bi[ng], 0.f);
                    zh[rr * H + (((col >> 3) ^ (rr & 7)) << 3) + (col & 7)] = f2bf(x);
                }
            }
        __syncthreads();   // writes visible
    }

    // ---- layer 4: per-mt MFMA + immediate atomic scatter (VMEM/MFMA overlap) ----
    {
        const u16* wl = wfbase + 2 * 32768;
#pragma unroll
        for (int ng = 0; ng < 2; ++ng)
#pragma unroll
            for (int ks = 0; ks < 4; ++ks) {
                int nt = 2 * w + ng;
                Bh[ng][ks] = *reinterpret_cast<const short8*>(wl + ((nt * 4 + ks) * 64 + lane) * 8);
                Bl[ng][ks] = *reinterpret_cast<const short8*>(wl + ((32 + nt * 4 + ks) * 64 + lane) * 8);
            }
        const float* bb = bb4 + t * H;
        float bi[2];
#pragma unroll
        for (int ng = 0; ng < 2; ++ng) bi[ng] = bb[(2 * w + ng) * 16 + (lane & 15)];
        int col0 = (2 * w) * 16 + (lane & 15);
        int col1 = col0 + 16;
#pragma unroll 1
        for (int mt = 0; mt < 8; ++mt) {
            short8 Ah[4];
            int rr = mt * 16 + (lane & 15);
#pragma unroll
            for (int ks = 0; ks < 4; ++ks) {
                int ch = ks * 4 + (lane >> 4);
                Ah[ks] = *reinterpret_cast<const short8*>(&zh[rr * H + ((ch ^ (rr & 7)) << 3)]);
            }
            f32x4 a0 = (f32x4){0.f, 0.f, 0.f, 0.f};
            f32x4 a1 = (f32x4){0.f, 0.f, 0.f, 0.f};
#pragma unroll
            for (int ks = 0; ks < 4; ++ks) {
                a0 = __builtin_amdgcn_mfma_f32_16x16x32_bf16(Ah[ks], Bh[0][ks], a0, 0, 0, 0);
                a0 = __builtin_amdgcn_mfma_f32_16x16x32_bf16(Ah[ks], Bl[0][ks], a0, 0, 0, 0);
                a1 = __builtin_amdgcn_mfma_f32_16x16x32_bf16(Ah[ks], Bh[1][ks], a1, 0, 0, 0);
                a1 = __builtin_amdgcn_mfma_f32_16x16x32_bf16(Ah[ks], Bl[1][ks], a1, 0, 0, 0);
            }
#pragma unroll
            for (int r = 0; r < 4; ++r) {
                int d = sdst[mt * 16 + (lane >> 4) * 4 + r];
                float* mrow = msg + (size_t)d * MSGW + t * H;
                atomicAdd(mrow + col0, a0[r] + bi[0]);
                atomicAdd(mrow + col1, a1[r] + bi[1]);
            }
        }
    }
}

// ---------------- LSTM pointwise + h frag pack (kt 24:28) ----------------
__global__ __launch_bounds__(256) void k_lstm(const float* __restrict__ gates,
                                              float* __restrict__ cst,
                                              float* __restrict__ rnn_h,
                                              u16* __restrict__ Ap, size_t aplane) {
    __shared__ float sh[16][132];
    int mtile = blockIdx.x, tid = threadIdx.x;
#pragma unroll
    for (int e = 0; e < 8; ++e) {
        int idx = e * 256 + tid;
        int row = idx >> 7, c = idx & 127;
        int grow = mtile * 16 + row;
        const float* g = gates + (size_t)grow * G4;
        float ig = g[c], fg = g[128 + c], gg = g[256 + c], og = g[384 + c];
        size_t ci = (size_t)grow * H + c;
        float c_old = cst[ci];
        float i_s = 1.f / (1.f + expf(-ig));
        float f_s = 1.f / (1.f + expf(-fg));
        float o_s = 1.f / (1.f + expf(-og));
        float c_new = f_s * c_old + i_s * tanhf(gg);
        float h_new = o_s * tanhf(c_new);
        cst[ci] = c_new;
        rnn_h[ci] = h_new;
        sh[row][c] = h_new;
    }
    __syncthreads();
    int kt = tid >> 6, lane = tid & 63;
    int row = lane & 15, c0 = kt * 32 + ((lane >> 4) << 3);
    ushort8 hh, ll;
#pragma unroll
    for (int i = 0; i < 8; ++i) {
        float x = sh[row][c0 + i];
        u16 h = f2bf(x);
        hh[i] = h;
        ll[i] = f2bf(x - bf2f(h));
    }
    size_t fo = ((size_t)(mtile * AKT + 24 + kt) * 64 + lane) * 8;
    *reinterpret_cast<ushort8*>(Ap + fo) = hh;
    *reinterpret_cast<ushort8*>(Ap + aplane + fo) = ll;
}

// ---------------- logits ----------------
__global__ __launch_bounds__(256) void k_logits(const float* __restrict__ h,
                                                const float* __restrict__ oemb,
                                                float* __restrict__ out) {
    __shared__ float oe[17][129];
    int b = blockIdx.x, tid = threadIdx.x;
    for (int id = tid; id < 17 * 128; id += 256) {
        int r = id >> 7, c = id & 127;
        oe[r][c] = oemb[(b * 17 + r) * H + c];
    }
    __syncthreads();
    const float* hr = h + (size_t)(b * 256 + tid) * H;
    float acc[17] = {};
    for (int v = 0; v < 32; ++v) {
        float4 hv = reinterpret_cast<const float4*>(hr)[v];
#pragma unroll
        for (int cls = 0; cls < 17; ++cls) {
            acc[cls] = fmaf(hv.x, oe[cls][v * 4 + 0],
                       fmaf(hv.y, oe[cls][v * 4 + 1],
                       fmaf(hv.z, oe[cls][v * 4 + 2],
                       fmaf(hv.w, oe[cls][v * 4 + 3], acc[cls]))));
        }
    }
    float* op = out + (size_t)(b * 256 + tid) * 17;
#pragma unroll
    for (int cls = 0; cls < 17; ++cls) op[cls] = acc[cls];
}

extern "C" void kernel_launch(void* const* d_in, const int* in_sizes, int n_in,
                              void* d_out, int out_size, void* d_ws, size_t ws_size,
                              hipStream_t stream) {
    (void)in_sizes; (void)n_in; (void)out_size; (void)ws_size;
    const int*   edges = (const int*)d_in[0];
    const int*   q     = (const int*)d_in[1];
    const float* emb   = (const float*)d_in[2];
    const float* oemb  = (const float*)d_in[3];
    const float* W1    = (const float*)d_in[4];
    const float* b1    = (const float*)d_in[5];
    const float* W2    = (const float*)d_in[6];
    const float* b2    = (const float*)d_in[7];
    const float* W3    = (const float*)d_in[8];
    const float* b3    = (const float*)d_in[9];
    const float* W4    = (const float*)d_in[10];
    const float* b4    = (const float*)d_in[11];
    const float* Wih   = (const float*)d_in[12];
    const float* Whh   = (const float*)d_in[13];
    float* out = (float*)d_out;

    // ---- workspace layout (bytes, 256-aligned) ----
    char* wsp = (char*)d_ws;
    size_t off = 0;
    auto alloc = [&](size_t bytes) { void* p = wsp + off; off = (off + bytes + 255) & ~(size_t)255; return p; };
    float* msg    = (float*)alloc((size_t)NCELL * MSGW * 4);
    u16*   P      = (u16*)  alloc((size_t)NCELL * 1152 * 2);
    float* gates  = (float*)P;                                      // alias
    float* rnn_h  = (float*)alloc((size_t)NCELL * H * 4);
    float* cst    = (float*)alloc((size_t)NCELL * H * 4);
    u16*   Ps0    = (u16*)  alloc((size_t)NCLU * H * 2);
    float* avg    = (float*)alloc((size_t)64 * H * 4);
    size_t aplane = (size_t)NCELL * 896;
    u16*   Ap     = (u16*)  alloc(aplane * 2 * 2);
    u16*   WF     = (u16*)  alloc((size_t)983040 * 2);
    size_t bwpl   = (size_t)512 * 896;
    u16*   Bw     = (u16*)  alloc(bwpl * 2 * 2);
    size_t bppl   = (size_t)1152 * 128;
    u16*   Bp     = (u16*)  alloc(bppl * 2 * 2);

    // ---- one-time prep ----
    k_avg<<<64, 128, 0, stream>>>(emb, avg);
    k_init<<<1024, 256, 0, stream>>>(q, emb, avg, Ap, aplane, rnn_h, cst);
    k_prepw<<<240, 256, 0, stream>>>(W2, W3, W4, WF);
    {
        dim3 g(32, 7);
        k_packBw<<<g, 256, 0, stream>>>(Wih, Whh, Bw, bwpl);
    }
    k_packBp<<<72, 256, 0, stream>>>(W1, Bp, bppl);
    {
        dim3 g0(17, 2);
        k_gemm32<<<g0, 256, 0, stream>>>(emb, H, W1, H, Ps0, H, H);
    }

    for (int s = 0; s < SSTEPS; ++s) {
        k_zeromsg<<<NCELL * MSGW / 4 / 256, 256, 0, stream>>>(msg);
        // P = h @ Wproj (bf16 out); A-frags: kt 0:4 (cell_x) at s=0 else kt 24:28 (h)
        {
            dim3 g(128, 9);
            k_gemm_bf<<<g, 256, 0, stream>>>(Ap, aplane, (s == 0) ? 0 : 24,
                                             Bp, bppl, 4, 4, nullptr, P, 1152);
        }
        k_edge<<<NT * (NE / EB), 256, 0, stream>>>(edges, P, Ps0, WF,
                                                   b1, b2, b3, b4, msg);
        {
            dim3 g(1024, 5);
            k_packmsg<<<g, 256, 0, stream>>>(msg, Ap, aplane);
        }
        // gates = [cell_x, msg, h] @ [Wih; Whh]  (K = 768 at s=0, 896 else)
        {
            dim3 g(128, 4);
            k_gemm_bf<<<g, 256, 0, stream>>>(Ap, aplane, 0, Bw, bwpl, AKT,
                                             (s == 0) ? 24 : 28, gates, nullptr, G4);
        }
        k_lstm<<<1024, 256, 0, stream>>>(gates, cst, rnn_h, Ap, aplane);
        k_logits<<<64, 256, 0, stream>>>(rnn_h, oemb, out + (size_t)s * NCELL * 17);
    }
}

// Round 9
// 1553.411 us; speedup vs baseline: 1.6690x; 1.0857x over previous
//
#include <hip/hip_runtime.h>
#include <hip/hip_fp16.h>
#include <math.h>

#define H 128
#define SSTEPS 3
#define NE 131072
#define NT 5
#define NCELL 16384
#define NCLU 1088
#define G4 512
#define MSGW 640     // 5*H message block (fp16, column-permuted per type)
#define AKT 28       // Apack kt count (896 K-cols / 32)
#define EB 128

typedef unsigned short u16;
typedef unsigned int u32;
typedef __attribute__((ext_vector_type(8))) short short8;
typedef __attribute__((ext_vector_type(8))) unsigned short ushort8;
typedef __attribute__((ext_vector_type(4))) float f32x4;

__device__ __forceinline__ u16 f2bf(float f) {
    unsigned int u = __float_as_uint(f);
    u += 0x7fffu + ((u >> 16) & 1u);
    return (u16)(u >> 16);
}
__device__ __forceinline__ float bf2f(u16 h) {
    return __uint_as_float(((unsigned int)h) << 16);
}

// ---------------- avg of class embeddings 1..16 per batch ----------------
__global__ __launch_bounds__(128) void k_avg(const float* __restrict__ emb,
                                             float* __restrict__ avg) {
    int b = blockIdx.x, hc = threadIdx.x;
    float s = 0.f;
#pragma unroll
    for (int r = 1; r <= 16; ++r) s += emb[(b * 17 + r) * H + hc];
    avg[b * H + hc] = s * (1.0f / 16.0f);
}

// ---------------- init: cell_x -> Apack kt 0:4 (hi/lo); zero rnn_h, cst ----------------
__global__ __launch_bounds__(256) void k_init(const int* __restrict__ q,
                                              const float* __restrict__ emb,
                                              const float* __restrict__ avg,
                                              u16* __restrict__ Ap, size_t aplane,
                                              float* __restrict__ rnn_h,
                                              float* __restrict__ cst) {
    __shared__ float sx[16][132];
    int mtile = blockIdx.x, tid = threadIdx.x;
#pragma unroll
    for (int e = 0; e < 8; ++e) {
        int idx = e * 256 + tid;
        int row = idx >> 7, c = idx & 127;
        int grow = mtile * 16 + row;
        int b = grow >> 8;
        int qi = q[grow];
        const float* src = (qi == 0) ? (avg + b * H) : (emb + (b * 17 + qi) * H);
        float v = src[c];
        sx[row][c] = v;
        rnn_h[(size_t)grow * H + c] = 0.f;
        cst[(size_t)grow * H + c] = 0.f;
    }
    __syncthreads();
    int kt = tid >> 6, lane = tid & 63;
    int row = lane & 15, c0 = kt * 32 + ((lane >> 4) << 3);
    ushort8 hh, ll;
#pragma unroll
    for (int i = 0; i < 8; ++i) {
        float x = sx[row][c0 + i];
        u16 h = f2bf(x);
        hh[i] = h;
        ll[i] = f2bf(x - bf2f(h));
    }
    size_t fo = ((size_t)(mtile * AKT + kt) * 64 + lane) * 8;
    *reinterpret_cast<ushort8*>(Ap + fo) = hh;
    *reinterpret_cast<ushort8*>(Ap + aplane + fo) = ll;
}

// ---------------- zero msg buffer (fp16, 21MB) ----------------
__global__ __launch_bounds__(256) void k_zeromsg(__half* __restrict__ msg) {
    int idx = blockIdx.x * 256 + threadIdx.x;   // NCELL*MSGW/8 chunks of 16B
    reinterpret_cast<float4*>(msg)[idx] = make_float4(0.f, 0.f, 0.f, 0.f);
}

// ---------------- fp32 GEMM -> bf16 out (Ps0 only; tiny) ----------------
__global__ __launch_bounds__(256) void k_gemm32(const float* __restrict__ A, int lda,
                                                const float* __restrict__ B, int ldb,
                                                u16* __restrict__ C, int ldc, int K) {
    __shared__ float As[64][33];
    __shared__ float Bs[32][64];
    int tid = threadIdx.x;
    int ty = tid >> 4, tx = tid & 15;
    int rbase = blockIdx.x * 64, cbase = blockIdx.y * 64;
    float acc[4][4] = {};
    for (int k0 = 0; k0 < K; k0 += 32) {
        __syncthreads();
#pragma unroll
        for (int i = 0; i < 8; ++i) {
            int id = tid + i * 256;
            int r = id >> 5, c = id & 31;
            As[r][c] = A[(size_t)(rbase + r) * lda + k0 + c];
        }
#pragma unroll
        for (int i = 0; i < 8; ++i) {
            int id = tid + i * 256;
            int r = id >> 6, c = id & 63;
            Bs[r][c] = B[(size_t)(k0 + r) * ldb + cbase + c];
        }
        __syncthreads();
#pragma unroll 8
        for (int kk = 0; kk < 32; ++kk) {
            float a[4], bv[4];
#pragma unroll
            for (int i = 0; i < 4; ++i) a[i] = As[ty * 4 + i][kk];
#pragma unroll
            for (int j = 0; j < 4; ++j) bv[j] = Bs[kk][tx * 4 + j];
#pragma unroll
            for (int i = 0; i < 4; ++i)
#pragma unroll
                for (int j = 0; j < 4; ++j) acc[i][j] = fmaf(a[i], bv[j], acc[i][j]);
        }
    }
#pragma unroll
    for (int i = 0; i < 4; ++i)
#pragma unroll
        for (int j = 0; j < 4; ++j)
            C[(size_t)(rbase + ty * 4 + i) * ldc + cbase + tx * 4 + j] = f2bf(acc[i][j]);
}

// ---------------- W2/W3/W4 -> fragment-packed bf16 hi/lo ----------------
__global__ __launch_bounds__(256) void k_prepw(const float* __restrict__ W2,
                                               const float* __restrict__ W3,
                                               const float* __restrict__ W4,
                                               u16* __restrict__ WF) {
    int bid = blockIdx.x;                  // 240 = 5*3*2*8
    int t = bid / 48;
    int l = (bid / 16) % 3;
    int p = (bid / 8) % 2;
    int nt = bid % 8;
    int tid = threadIdx.x;
    int ks = tid >> 6, lane = tid & 63;
    const float* W = (l == 0 ? W2 : l == 1 ? W3 : W4) + t * 16384;
    int n = nt * 16 + (lane & 15);
    int kb = ks * 32 + (lane >> 4) * 8;
    ushort8 o;
#pragma unroll
    for (int i = 0; i < 8; ++i) {
        float w = W[(size_t)(kb + i) * H + n];
        u16 h = f2bf(w);
        o[i] = (p == 0) ? h : f2bf(w - bf2f(h));
    }
    size_t base = ((size_t)((((t * 3 + l) * 2 + p) * 8 + nt) * 4 + ks) * 64 + lane) * 8;
    *reinterpret_cast<ushort8*>(WF + base) = o;
}

// ---------------- pack [Wih;Whh] -> B-frags hi/lo ----------------
__global__ __launch_bounds__(256) void k_packBw(const float* __restrict__ Wih,
                                                const float* __restrict__ Whh,
                                                u16* __restrict__ Bw, size_t bplane) {
    int nt = blockIdx.x;                           // 32
    int kt = blockIdx.y * 4 + (threadIdx.x >> 6);  // grid.y=7 -> 0..27
    int lane = threadIdx.x & 63;
    int n = nt * 16 + (lane & 15);
    int k0 = kt * 32 + ((lane >> 4) << 3);
    ushort8 hh, ll;
#pragma unroll
    for (int i = 0; i < 8; ++i) {
        int k = k0 + i;
        float wv = (k < 768) ? Wih[(size_t)k * G4 + n] : Whh[(size_t)(k - 768) * G4 + n];
        u16 h = f2bf(wv);
        hh[i] = h;
        ll[i] = f2bf(wv - bf2f(h));
    }
    size_t fo = ((size_t)(nt * AKT + kt) * 64 + lane) * 8;
    *reinterpret_cast<ushort8*>(Bw + fo) = hh;
    *reinterpret_cast<ushort8*>(Bw + bplane + fo) = ll;
}

// ---------------- pack projection weights (from W1) -> B-frags hi/lo ----------------
__global__ __launch_bounds__(256) void k_packBp(const float* __restrict__ W1,
                                                u16* __restrict__ Bp, size_t bplane) {
    int nt = blockIdx.x;               // 72
    int kt = threadIdx.x >> 6;         // 0..3
    int lane = threadIdx.x & 63;
    int n = nt * 16 + (lane & 15);
    int k0 = kt * 32 + ((lane >> 4) << 3);
    int t, roff, j;
    if (n < 640) { t = n >> 7; j = n & 127; roff = 128; }
    else { int m = n - 640; t = (m >> 7) + 1; j = m & 127; roff = 0; }
    ushort8 hh, ll;
#pragma unroll
    for (int i = 0; i < 8; ++i) {
        float wv = W1[((size_t)t * 256 + roff + k0 + i) * H + j];
        u16 h = f2bf(wv);
        hh[i] = h;
        ll[i] = f2bf(wv - bf2f(h));
    }
    size_t fo = ((size_t)(nt * 4 + kt) * 64 + lane) * 8;
    *reinterpret_cast<ushort8*>(Bp + fo) = hh;
    *reinterpret_cast<ushort8*>(Bp + bplane + fo) = ll;
}

// ---------------- pack msg fp16 (permuted cols) -> Apack kt 4:24 hi/lo ----------------
// permutation within a 128-col type block: f -> (f>>5)*32 + (f&15)*2 + ((f>>4)&1)
__global__ __launch_bounds__(256) void k_packmsg(const __half* __restrict__ msg,
                                                 u16* __restrict__ Ap, size_t aplane) {
    int mtile = blockIdx.x;
    int ktl = blockIdx.y * 4 + (threadIdx.x >> 6);   // 0..19
    int lane = threadIdx.x & 63;
    int row = mtile * 16 + (lane & 15);
    int c0 = ktl * 32 + ((lane >> 4) << 3);
    const __half* mrow = msg + (size_t)row * MSGW;
    ushort8 hh, ll;
#pragma unroll
    for (int i = 0; i < 8; ++i) {
        int fg = c0 + i;
        int tt = fg >> 7, fl = fg & 127;
        int pos = tt * 128 + ((fl >> 5) << 5) + ((fl & 15) << 1) + ((fl >> 4) & 1);
        float x = __half2float(mrow[pos]);
        u16 h = f2bf(x);
        hh[i] = h;
        ll[i] = f2bf(x - bf2f(h));
    }
    size_t fo = ((size_t)(mtile * AKT + 4 + ktl) * 64 + lane) * 8;
    *reinterpret_cast<ushort8*>(Ap + fo) = hh;
    *reinterpret_cast<ushort8*>(Ap + aplane + fo) = ll;
}

// ---------------- MFMA GEMM, 3-term split bf16, frag inputs, no LDS ----------------
__global__ __launch_bounds__(256) void k_gemm_bf(const u16* __restrict__ Ap, size_t aplane,
                                                 int aktbase,
                                                 const u16* __restrict__ Bp, size_t bplane,
                                                 int bKT, int nkt,
                                                 float* __restrict__ Cf, u16* __restrict__ Ch,
                                                 int ldc) {
    int tid = threadIdx.x;
    int w = tid >> 6, lane = tid & 63;
    int wr = w >> 1, wc = w & 1;
    int mtb = blockIdx.x * 8 + wr * 4;
    int ntb = blockIdx.y * 8 + wc * 4;
    f32x4 acc[4][4] = {};
    for (int kk = 0; kk < nkt; ++kk) {
        short8 Ah[4], Al[4], Bh[4], Bl[4];
#pragma unroll
        for (int m = 0; m < 4; ++m) {
            size_t fo = ((size_t)((mtb + m) * AKT + aktbase + kk) * 64 + lane) * 8;
            Ah[m] = *reinterpret_cast<const short8*>(Ap + fo);
            Al[m] = *reinterpret_cast<const short8*>(Ap + aplane + fo);
        }
#pragma unroll
        for (int n = 0; n < 4; ++n) {
            size_t fo = ((size_t)((ntb + n) * bKT + kk) * 64 + lane) * 8;
            Bh[n] = *reinterpret_cast<const short8*>(Bp + fo);
            Bl[n] = *reinterpret_cast<const short8*>(Bp + bplane + fo);
        }
#pragma unroll
        for (int m = 0; m < 4; ++m)
#pragma unroll
            for (int n = 0; n < 4; ++n) {
                acc[m][n] = __builtin_amdgcn_mfma_f32_16x16x32_bf16(Ah[m], Bh[n], acc[m][n], 0, 0, 0);
                acc[m][n] = __builtin_amdgcn_mfma_f32_16x16x32_bf16(Ah[m], Bl[n], acc[m][n], 0, 0, 0);
                acc[m][n] = __builtin_amdgcn_mfma_f32_16x16x32_bf16(Al[m], Bh[n], acc[m][n], 0, 0, 0);
            }
    }
#pragma unroll
    for (int m = 0; m < 4; ++m)
#pragma unroll
        for (int r = 0; r < 4; ++r) {
            int row = (mtb + m) * 16 + (lane >> 4) * 4 + r;
#pragma unroll
            for (int n = 0; n < 4; ++n) {
                int col = (ntb + n) * 16 + (lane & 15);
                float v = acc[m][n][r];
                if (Ch) Ch[(size_t)row * ldc + col] = f2bf(v);
                else Cf[(size_t)row * ldc + col] = v;
            }
        }
}

// ---------------- fused per-edge MLP; packed-fp16 atomic scatter ----------------
__global__ __launch_bounds__(256, 4) void k_edge(const int* __restrict__ edges,
                                                 const u16* __restrict__ P,
                                                 const u16* __restrict__ Ps0,
                                                 const u16* __restrict__ WF,
                                                 const float* __restrict__ bb1,
                                                 const float* __restrict__ bb2,
                                                 const float* __restrict__ bb3,
                                                 const float* __restrict__ bb4,
                                                 __half* __restrict__ msg) {
    __shared__ u16 zh[EB * H];    // 32KB, 16B-chunk XOR swizzle
    __shared__ int sdst[EB];
    int tid = threadIdx.x;
    int w = tid >> 6, lane = tid & 63;
    int bid = blockIdx.x;
    int t = bid >> 10, tile = bid & 1023;
    int ebase = tile * EB;

    // ---- layer 1 ----
    {
        int row = tid >> 1, half = tid & 1;
        int e = ebase + row;
        int sn = edges[(t * 2) * NE + e];
        int dn = edges[(t * 2 + 1) * NE + e];
        if (half == 0) sdst[row] = dn;
        const u16* ps = (t == 0) ? Ps0 + (size_t)sn * H
                                 : P + (size_t)sn * 1152 + 640 + (t - 1) * H;
        const u16* pd = P + (size_t)dn * 1152 + t * H;
        const float* bb = bb1 + t * H;
#pragma unroll
        for (int cc = 0; cc < 8; ++cc) {
            int c8 = half * 8 + cc;
            ushort8 a = *reinterpret_cast<const ushort8*>(ps + c8 * 8);
            ushort8 d = *reinterpret_cast<const ushort8*>(pd + c8 * 8);
            float4 b0 = *reinterpret_cast<const float4*>(bb + c8 * 8);
            float4 b1v = *reinterpret_cast<const float4*>(bb + c8 * 8 + 4);
            float bv[8] = {b0.x, b0.y, b0.z, b0.w, b1v.x, b1v.y, b1v.z, b1v.w};
            ushort8 hh;
#pragma unroll
            for (int i = 0; i < 8; ++i)
                hh[i] = f2bf(fmaxf(bf2f(a[i]) + bf2f(d[i]) + bv[i], 0.f));
            *reinterpret_cast<ushort8*>(&zh[row * H + ((c8 ^ (row & 7)) << 3)]) = hh;
        }
    }
    __syncthreads();

    const u16* wfbase = WF + (size_t)(t * 3) * 32768;
    short8 Bh[2][4], Bl[2][4];

    // ---- layers 2,3 ----
#pragma unroll 1
    for (int l = 0; l < 2; ++l) {
        const u16* wl = wfbase + l * 32768;
#pragma unroll
        for (int ng = 0; ng < 2; ++ng)
#pragma unroll
            for (int ks = 0; ks < 4; ++ks) {
                int nt = 2 * w + ng;
                Bh[ng][ks] = *reinterpret_cast<const short8*>(wl + ((nt * 4 + ks) * 64 + lane) * 8);
                Bl[ng][ks] = *reinterpret_cast<const short8*>(wl + ((32 + nt * 4 + ks) * 64 + lane) * 8);
            }
        f32x4 acc[8][2];
#pragma unroll
        for (int mt = 0; mt < 8; ++mt)
#pragma unroll
            for (int ng = 0; ng < 2; ++ng)
                acc[mt][ng] = (f32x4){0.f, 0.f, 0.f, 0.f};
#pragma unroll
        for (int mt = 0; mt < 8; ++mt) {
            short8 Ah[4];
            int rr = mt * 16 + (lane & 15);
#pragma unroll
            for (int ks = 0; ks < 4; ++ks) {
                int ch = ks * 4 + (lane >> 4);
                Ah[ks] = *reinterpret_cast<const short8*>(&zh[rr * H + ((ch ^ (rr & 7)) << 3)]);
            }
#pragma unroll
            for (int ng = 0; ng < 2; ++ng)
#pragma unroll
                for (int ks = 0; ks < 4; ++ks) {
                    acc[mt][ng] = __builtin_amdgcn_mfma_f32_16x16x32_bf16(Ah[ks], Bh[ng][ks], acc[mt][ng], 0, 0, 0);
                    acc[mt][ng] = __builtin_amdgcn_mfma_f32_16x16x32_bf16(Ah[ks], Bl[ng][ks], acc[mt][ng], 0, 0, 0);
                }
        }
        __syncthreads();
        const float* bb = (l == 0 ? bb2 : bb3) + t * H;
        float bi[2];
#pragma unroll
        for (int ng = 0; ng < 2; ++ng) bi[ng] = bb[(2 * w + ng) * 16 + (lane & 15)];
#pragma unroll
        for (int mt = 0; mt < 8; ++mt)
#pragma unroll
            for (int ng = 0; ng < 2; ++ng) {
                int col = (2 * w + ng) * 16 + (lane & 15);
#pragma unroll
                for (int r = 0; r < 4; ++r) {
                    int rr = mt * 16 + (lane >> 4) * 4 + r;
                    float x = fmaxf(acc[mt][ng][r] + bi[ng], 0.f);
                    zh[rr * H + (((col >> 3) ^ (rr & 7)) << 3) + (col & 7)] = f2bf(x);
                }
            }
        __syncthreads();
    }

    // ---- layer 4: per-mt MFMA + packed-fp16 atomic scatter ----
    {
        const u16* wl = wfbase + 2 * 32768;
#pragma unroll
        for (int ng = 0; ng < 2; ++ng)
#pragma unroll
            for (int ks = 0; ks < 4; ++ks) {
                int nt = 2 * w + ng;
                Bh[ng][ks] = *reinterpret_cast<const short8*>(wl + ((nt * 4 + ks) * 64 + lane) * 8);
                Bl[ng][ks] = *reinterpret_cast<const short8*>(wl + ((32 + nt * 4 + ks) * 64 + lane) * 8);
            }
        const float* bb = bb4 + t * H;
        float bi[2];
#pragma unroll
        for (int ng = 0; ng < 2; ++ng) bi[ng] = bb[(2 * w + ng) * 16 + (lane & 15)];
        // permuted column pair base for this lane: features (2w)*16+c and (2w+1)*16+c
        int pos = (w * 16 + (lane & 15)) * 2;   // even -> 4B-aligned __half2
#pragma unroll 1
        for (int mt = 0; mt < 8; ++mt) {
            short8 Ah[4];
            int rr = mt * 16 + (lane & 15);
#pragma unroll
            for (int ks = 0; ks < 4; ++ks) {
                int ch = ks * 4 + (lane >> 4);
                Ah[ks] = *reinterpret_cast<const short8*>(&zh[rr * H + ((ch ^ (rr & 7)) << 3)]);
            }
            f32x4 a0 = (f32x4){0.f, 0.f, 0.f, 0.f};
            f32x4 a1 = (f32x4){0.f, 0.f, 0.f, 0.f};
#pragma unroll
            for (int ks = 0; ks < 4; ++ks) {
                a0 = __builtin_amdgcn_mfma_f32_16x16x32_bf16(Ah[ks], Bh[0][ks], a0, 0, 0, 0);
                a0 = __builtin_amdgcn_mfma_f32_16x16x32_bf16(Ah[ks], Bl[0][ks], a0, 0, 0, 0);
                a1 = __builtin_amdgcn_mfma_f32_16x16x32_bf16(Ah[ks], Bh[1][ks], a1, 0, 0, 0);
                a1 = __builtin_amdgcn_mfma_f32_16x16x32_bf16(Ah[ks], Bl[1][ks], a1, 0, 0, 0);
            }
#pragma unroll
            for (int r = 0; r < 4; ++r) {
                int d = sdst[mt * 16 + (lane >> 4) * 4 + r];
                __half2* mp = reinterpret_cast<__half2*>(msg + (size_t)d * MSGW + t * H + pos);
                unsafeAtomicAdd(mp, __floats2half2_rn(a0[r] + bi[0], a1[r] + bi[1]));
            }
        }
    }
}

// ---------------- LSTM pointwise + h frag pack (kt 24:28) ----------------
__global__ __launch_bounds__(256) void k_lstm(const float* __restrict__ gates,
                                              float* __restrict__ cst,
                                              float* __restrict__ rnn_h,
                                              u16* __restrict__ Ap, size_t aplane) {
    __shared__ float sh[16][132];
    int mtile = blockIdx.x, tid = threadIdx.x;
#pragma unroll
    for (int e = 0; e < 8; ++e) {
        int idx = e * 256 + tid;
        int row = idx >> 7, c = idx & 127;
        int grow = mtile * 16 + row;
        const float* g = gates + (size_t)grow * G4;
        float ig = g[c], fg = g[128 + c], gg = g[256 + c], og = g[384 + c];
        size_t ci = (size_t)grow * H + c;
        float c_old = cst[ci];
        float i_s = 1.f / (1.f + expf(-ig));
        float f_s = 1.f / (1.f + expf(-fg));
        float o_s = 1.f / (1.f + expf(-og));
        float c_new = f_s * c_old + i_s * tanhf(gg);
        float h_new = o_s * tanhf(c_new);
        cst[ci] = c_new;
        rnn_h[ci] = h_new;
        sh[row][c] = h_new;
    }
    __syncthreads();
    int kt = tid >> 6, lane = tid & 63;
    int row = lane & 15, c0 = kt * 32 + ((lane >> 4) << 3);
    ushort8 hh, ll;
#pragma unroll
    for (int i = 0; i < 8; ++i) {
        float x = sh[row][c0 + i];
        u16 h = f2bf(x);
        hh[i] = h;
        ll[i] = f2bf(x - bf2f(h));
    }
    size_t fo = ((size_t)(mtile * AKT + 24 + kt) * 64 + lane) * 8;
    *reinterpret_cast<ushort8*>(Ap + fo) = hh;
    *reinterpret_cast<ushort8*>(Ap + aplane + fo) = ll;
}

// ---------------- logits ----------------
__global__ __launch_bounds__(256) void k_logits(const float* __restrict__ h,
                                                const float* __restrict__ oemb,
                                                float* __restrict__ out) {
    __shared__ float oe[17][129];
    int b = blockIdx.x, tid = threadIdx.x;
    for (int id = tid; id < 17 * 128; id += 256) {
        int r = id >> 7, c = id & 127;
        oe[r][c] = oemb[(b * 17 + r) * H + c];
    }
    __syncthreads();
    const float* hr = h + (size_t)(b * 256 + tid) * H;
    float acc[17] = {};
    for (int v = 0; v < 32; ++v) {
        float4 hv = reinterpret_cast<const float4*>(hr)[v];
#pragma unroll
        for (int cls = 0; cls < 17; ++cls) {
            acc[cls] = fmaf(hv.x, oe[cls][v * 4 + 0],
                       fmaf(hv.y, oe[cls][v * 4 + 1],
                       fmaf(hv.z, oe[cls][v * 4 + 2],
                       fmaf(hv.w, oe[cls][v * 4 + 3], acc[cls]))));
        }
    }
    float* op = out + (size_t)(b * 256 + tid) * 17;
#pragma unroll
    for (int cls = 0; cls < 17; ++cls) op[cls] = acc[cls];
}

extern "C" void kernel_launch(void* const* d_in, const int* in_sizes, int n_in,
                              void* d_out, int out_size, void* d_ws, size_t ws_size,
                              hipStream_t stream) {
    (void)in_sizes; (void)n_in; (void)out_size; (void)ws_size;
    const int*   edges = (const int*)d_in[0];
    const int*   q     = (const int*)d_in[1];
    const float* emb   = (const float*)d_in[2];
    const float* oemb  = (const float*)d_in[3];
    const float* W1    = (const float*)d_in[4];
    const float* b1    = (const float*)d_in[5];
    const float* W2    = (const float*)d_in[6];
    const float* b2    = (const float*)d_in[7];
    const float* W3    = (const float*)d_in[8];
    const float* b3    = (const float*)d_in[9];
    const float* W4    = (const float*)d_in[10];
    const float* b4    = (const float*)d_in[11];
    const float* Wih   = (const float*)d_in[12];
    const float* Whh   = (const float*)d_in[13];
    float* out = (float*)d_out;

    // ---- workspace layout (bytes, 256-aligned) ----
    char* wsp = (char*)d_ws;
    size_t off = 0;
    auto alloc = [&](size_t bytes) { void* p = wsp + off; off = (off + bytes + 255) & ~(size_t)255; return p; };
    __half* msg   = (__half*)alloc((size_t)NCELL * MSGW * 2);       // 21MB fp16
    u16*   P      = (u16*)  alloc((size_t)NCELL * 1152 * 2);
    float* gates  = (float*)P;                                      // alias
    float* rnn_h  = (float*)alloc((size_t)NCELL * H * 4);
    float* cst    = (float*)alloc((size_t)NCELL * H * 4);
    u16*   Ps0    = (u16*)  alloc((size_t)NCLU * H * 2);
    float* avg    = (float*)alloc((size_t)64 * H * 4);
    size_t aplane = (size_t)NCELL * 896;
    u16*   Ap     = (u16*)  alloc(aplane * 2 * 2);
    u16*   WF     = (u16*)  alloc((size_t)983040 * 2);
    size_t bwpl   = (size_t)512 * 896;
    u16*   Bw     = (u16*)  alloc(bwpl * 2 * 2);
    size_t bppl   = (size_t)1152 * 128;
    u16*   Bp     = (u16*)  alloc(bppl * 2 * 2);

    // ---- one-time prep ----
    k_avg<<<64, 128, 0, stream>>>(emb, avg);
    k_init<<<1024, 256, 0, stream>>>(q, emb, avg, Ap, aplane, rnn_h, cst);
    k_prepw<<<240, 256, 0, stream>>>(W2, W3, W4, WF);
    {
        dim3 g(32, 7);
        k_packBw<<<g, 256, 0, stream>>>(Wih, Whh, Bw, bwpl);
    }
    k_packBp<<<72, 256, 0, stream>>>(W1, Bp, bppl);
    {
        dim3 g0(17, 2);
        k_gemm32<<<g0, 256, 0, stream>>>(emb, H, W1, H, Ps0, H, H);
    }

    for (int s = 0; s < SSTEPS; ++s) {
        k_zeromsg<<<NCELL * MSGW / 8 / 256, 256, 0, stream>>>(msg);
        // P = h @ Wproj (bf16 out); A-frags: kt 0:4 (cell_x) at s=0 else kt 24:28 (h)
        {
            dim3 g(128, 9);
            k_gemm_bf<<<g, 256, 0, stream>>>(Ap, aplane, (s == 0) ? 0 : 24,
                                             Bp, bppl, 4, 4, nullptr, P, 1152);
        }
        k_edge<<<NT * (NE / EB), 256, 0, stream>>>(edges, P, Ps0, WF,
                                                   b1, b2, b3, b4, msg);
        {
            dim3 g(1024, 5);
            k_packmsg<<<g, 256, 0, stream>>>(msg, Ap, aplane);
        }
        // gates = [cell_x, msg, h] @ [Wih; Whh]  (K = 768 at s=0, 896 else)
        {
            dim3 g(128, 4);
            k_gemm_bf<<<g, 256, 0, stream>>>(Ap, aplane, 0, Bw, bwpl, AKT,
                                             (s == 0) ? 24 : 28, gates, nullptr, G4);
        }
        k_lstm<<<1024, 256, 0, stream>>>(gates, cst, rnn_h, Ap, aplane);
        k_logits<<<64, 256, 0, stream>>>(rnn_h, oemb, out + (size_t)s * NCELL * 17);
    }
}

// Round 10
// 1150.329 us; speedup vs baseline: 2.2539x; 1.3504x over previous
//
#include <hip/hip_runtime.h>
#include <hip/hip_fp16.h>
#include <math.h>

#define H 128
#define SSTEPS 3
#define NE 131072
#define NT 5
#define NCELL 16384
#define NCLU 1088
#define G4 512
#define MSGW 640     // 5*H message block (fp16, column-permuted per type)
#define AKT 28       // Apack kt count (896 K-cols / 32)
#define EB 128

typedef unsigned short u16;
typedef unsigned int u32;
typedef __attribute__((ext_vector_type(8))) short short8;
typedef __attribute__((ext_vector_type(8))) unsigned short ushort8;
typedef __attribute__((ext_vector_type(4))) unsigned short ushort4v;
typedef __attribute__((ext_vector_type(4))) float f32x4;

__device__ __forceinline__ u16 f2bf(float f) {
    unsigned int u = __float_as_uint(f);
    u += 0x7fffu + ((u >> 16) & 1u);
    return (u16)(u >> 16);
}
__device__ __forceinline__ float bf2f(u16 h) {
    return __uint_as_float(((unsigned int)h) << 16);
}

// ---------------- avg of class embeddings 1..16 per batch ----------------
__global__ __launch_bounds__(128) void k_avg(const float* __restrict__ emb,
                                             float* __restrict__ avg) {
    int b = blockIdx.x, hc = threadIdx.x;
    float s = 0.f;
#pragma unroll
    for (int r = 1; r <= 16; ++r) s += emb[(b * 17 + r) * H + hc];
    avg[b * H + hc] = s * (1.0f / 16.0f);
}

// ---------------- init: cell_x -> Apack kt 0:4 (hi/lo); zero rnn_h, cst ----------------
__global__ __launch_bounds__(256) void k_init(const int* __restrict__ q,
                                              const float* __restrict__ emb,
                                              const float* __restrict__ avg,
                                              u16* __restrict__ Ap, size_t aplane,
                                              float* __restrict__ rnn_h,
                                              float* __restrict__ cst) {
    __shared__ float sx[16][132];
    int mtile = blockIdx.x, tid = threadIdx.x;
#pragma unroll
    for (int e = 0; e < 8; ++e) {
        int idx = e * 256 + tid;
        int row = idx >> 7, c = idx & 127;
        int grow = mtile * 16 + row;
        int b = grow >> 8;
        int qi = q[grow];
        const float* src = (qi == 0) ? (avg + b * H) : (emb + (b * 17 + qi) * H);
        float v = src[c];
        sx[row][c] = v;
        rnn_h[(size_t)grow * H + c] = 0.f;
        cst[(size_t)grow * H + c] = 0.f;
    }
    __syncthreads();
    int kt = tid >> 6, lane = tid & 63;
    int row = lane & 15, c0 = kt * 32 + ((lane >> 4) << 3);
    ushort8 hh, ll;
#pragma unroll
    for (int i = 0; i < 8; ++i) {
        float x = sx[row][c0 + i];
        u16 h = f2bf(x);
        hh[i] = h;
        ll[i] = f2bf(x - bf2f(h));
    }
    size_t fo = ((size_t)(mtile * AKT + kt) * 64 + lane) * 8;
    *reinterpret_cast<ushort8*>(Ap + fo) = hh;
    *reinterpret_cast<ushort8*>(Ap + aplane + fo) = ll;
}

// ---------------- zero msg buffer (fp16, 21MB) ----------------
__global__ __launch_bounds__(256) void k_zeromsg(__half* __restrict__ msg) {
    int idx = blockIdx.x * 256 + threadIdx.x;
    reinterpret_cast<float4*>(msg)[idx] = make_float4(0.f, 0.f, 0.f, 0.f);
}

// ---------------- fp32 GEMM -> bf16 out (Ps0 only; tiny) ----------------
__global__ __launch_bounds__(256) void k_gemm32(const float* __restrict__ A, int lda,
                                                const float* __restrict__ B, int ldb,
                                                u16* __restrict__ C, int ldc, int K) {
    __shared__ float As[64][33];
    __shared__ float Bs[32][64];
    int tid = threadIdx.x;
    int ty = tid >> 4, tx = tid & 15;
    int rbase = blockIdx.x * 64, cbase = blockIdx.y * 64;
    float acc[4][4] = {};
    for (int k0 = 0; k0 < K; k0 += 32) {
        __syncthreads();
#pragma unroll
        for (int i = 0; i < 8; ++i) {
            int id = tid + i * 256;
            int r = id >> 5, c = id & 31;
            As[r][c] = A[(size_t)(rbase + r) * lda + k0 + c];
        }
#pragma unroll
        for (int i = 0; i < 8; ++i) {
            int id = tid + i * 256;
            int r = id >> 6, c = id & 63;
            Bs[r][c] = B[(size_t)(k0 + r) * ldb + cbase + c];
        }
        __syncthreads();
#pragma unroll 8
        for (int kk = 0; kk < 32; ++kk) {
            float a[4], bv[4];
#pragma unroll
            for (int i = 0; i < 4; ++i) a[i] = As[ty * 4 + i][kk];
#pragma unroll
            for (int j = 0; j < 4; ++j) bv[j] = Bs[kk][tx * 4 + j];
#pragma unroll
            for (int i = 0; i < 4; ++i)
#pragma unroll
                for (int j = 0; j < 4; ++j) acc[i][j] = fmaf(a[i], bv[j], acc[i][j]);
        }
    }
#pragma unroll
    for (int i = 0; i < 4; ++i)
#pragma unroll
        for (int j = 0; j < 4; ++j)
            C[(size_t)(rbase + ty * 4 + i) * ldc + cbase + tx * 4 + j] = f2bf(acc[i][j]);
}

// ---------------- W2/W3/W4 -> fragment-packed bf16 hi/lo ----------------
__global__ __launch_bounds__(256) void k_prepw(const float* __restrict__ W2,
                                               const float* __restrict__ W3,
                                               const float* __restrict__ W4,
                                               u16* __restrict__ WF) {
    int bid = blockIdx.x;                  // 240 = 5*3*2*8
    int t = bid / 48;
    int l = (bid / 16) % 3;
    int p = (bid / 8) % 2;
    int nt = bid % 8;
    int tid = threadIdx.x;
    int ks = tid >> 6, lane = tid & 63;
    const float* W = (l == 0 ? W2 : l == 1 ? W3 : W4) + t * 16384;
    int n = nt * 16 + (lane & 15);
    int kb = ks * 32 + (lane >> 4) * 8;
    ushort8 o;
#pragma unroll
    for (int i = 0; i < 8; ++i) {
        float w = W[(size_t)(kb + i) * H + n];
        u16 h = f2bf(w);
        o[i] = (p == 0) ? h : f2bf(w - bf2f(h));
    }
    size_t base = ((size_t)((((t * 3 + l) * 2 + p) * 8 + nt) * 4 + ks) * 64 + lane) * 8;
    *reinterpret_cast<ushort8*>(WF + base) = o;
}

// ---------------- pack [Wih;Whh] -> B-frags hi/lo ----------------
__global__ __launch_bounds__(256) void k_packBw(const float* __restrict__ Wih,
                                                const float* __restrict__ Whh,
                                                u16* __restrict__ Bw, size_t bplane) {
    int nt = blockIdx.x;                           // 32
    int kt = blockIdx.y * 4 + (threadIdx.x >> 6);  // grid.y=7 -> 0..27
    int lane = threadIdx.x & 63;
    int n = nt * 16 + (lane & 15);
    int k0 = kt * 32 + ((lane >> 4) << 3);
    ushort8 hh, ll;
#pragma unroll
    for (int i = 0; i < 8; ++i) {
        int k = k0 + i;
        float wv = (k < 768) ? Wih[(size_t)k * G4 + n] : Whh[(size_t)(k - 768) * G4 + n];
        u16 h = f2bf(wv);
        hh[i] = h;
        ll[i] = f2bf(wv - bf2f(h));
    }
    size_t fo = ((size_t)(nt * AKT + kt) * 64 + lane) * 8;
    *reinterpret_cast<ushort8*>(Bw + fo) = hh;
    *reinterpret_cast<ushort8*>(Bw + bplane + fo) = ll;
}

// ---------------- pack projection weights (from W1) -> B-frags hi/lo ----------------
__global__ __launch_bounds__(256) void k_packBp(const float* __restrict__ W1,
                                                u16* __restrict__ Bp, size_t bplane) {
    int nt = blockIdx.x;               // 72
    int kt = threadIdx.x >> 6;         // 0..3
    int lane = threadIdx.x & 63;
    int n = nt * 16 + (lane & 15);
    int k0 = kt * 32 + ((lane >> 4) << 3);
    int t, roff, j;
    if (n < 640) { t = n >> 7; j = n & 127; roff = 128; }
    else { int m = n - 640; t = (m >> 7) + 1; j = m & 127; roff = 0; }
    ushort8 hh, ll;
#pragma unroll
    for (int i = 0; i < 8; ++i) {
        float wv = W1[((size_t)t * 256 + roff + k0 + i) * H + j];
        u16 h = f2bf(wv);
        hh[i] = h;
        ll[i] = f2bf(wv - bf2f(h));
    }
    size_t fo = ((size_t)(nt * 4 + kt) * 64 + lane) * 8;
    *reinterpret_cast<ushort8*>(Bp + fo) = hh;
    *reinterpret_cast<ushort8*>(Bp + bplane + fo) = ll;
}

// ---------------- pack msg fp16 (permuted cols) -> Apack kt 4:24 hi/lo ----------------
// permutation within a 128-col type block: f -> (f>>5)*32 + (f&15)*2 + ((f>>4)&1)
__global__ __launch_bounds__(256) void k_packmsg(const __half* __restrict__ msg,
                                                 u16* __restrict__ Ap, size_t aplane) {
    int mtile = blockIdx.x;
    int ktl = blockIdx.y * 4 + (threadIdx.x >> 6);   // 0..19
    int lane = threadIdx.x & 63;
    int row = mtile * 16 + (lane & 15);
    int c0 = ktl * 32 + ((lane >> 4) << 3);
    const __half* mrow = msg + (size_t)row * MSGW;
    ushort8 hh, ll;
#pragma unroll
    for (int i = 0; i < 8; ++i) {
        int fg = c0 + i;
        int tt = fg >> 7, fl = fg & 127;
        int pos = tt * 128 + ((fl >> 5) << 5) + ((fl & 15) << 1) + ((fl >> 4) & 1);
        float x = __half2float(mrow[pos]);
        u16 h = f2bf(x);
        hh[i] = h;
        ll[i] = f2bf(x - bf2f(h));
    }
    size_t fo = ((size_t)(mtile * AKT + 4 + ktl) * 64 + lane) * 8;
    *reinterpret_cast<ushort8*>(Ap + fo) = hh;
    *reinterpret_cast<ushort8*>(Ap + aplane + fo) = ll;
}

// ---------------- MFMA GEMM, 3-term split bf16, frag inputs, no LDS ----------------
// psplit=1: bf16 out in per-type layout P9[col>>7][row][col&127]
__global__ __launch_bounds__(256) void k_gemm_bf(const u16* __restrict__ Ap, size_t aplane,
                                                 int aktbase,
                                                 const u16* __restrict__ Bp, size_t bplane,
                                                 int bKT, int nkt,
                                                 float* __restrict__ Cf, u16* __restrict__ Ch,
                                                 int ldc, int psplit) {
    int tid = threadIdx.x;
    int w = tid >> 6, lane = tid & 63;
    int wr = w >> 1, wc = w & 1;
    int mtb = blockIdx.x * 8 + wr * 4;
    int ntb = blockIdx.y * 8 + wc * 4;
    f32x4 acc[4][4] = {};
    for (int kk = 0; kk < nkt; ++kk) {
        short8 Ah[4], Al[4], Bh[4], Bl[4];
#pragma unroll
        for (int m = 0; m < 4; ++m) {
            size_t fo = ((size_t)((mtb + m) * AKT + aktbase + kk) * 64 + lane) * 8;
            Ah[m] = *reinterpret_cast<const short8*>(Ap + fo);
            Al[m] = *reinterpret_cast<const short8*>(Ap + aplane + fo);
        }
#pragma unroll
        for (int n = 0; n < 4; ++n) {
            size_t fo = ((size_t)((ntb + n) * bKT + kk) * 64 + lane) * 8;
            Bh[n] = *reinterpret_cast<const short8*>(Bp + fo);
            Bl[n] = *reinterpret_cast<const short8*>(Bp + bplane + fo);
        }
#pragma unroll
        for (int m = 0; m < 4; ++m)
#pragma unroll
            for (int n = 0; n < 4; ++n) {
                acc[m][n] = __builtin_amdgcn_mfma_f32_16x16x32_bf16(Ah[m], Bh[n], acc[m][n], 0, 0, 0);
                acc[m][n] = __builtin_amdgcn_mfma_f32_16x16x32_bf16(Ah[m], Bl[n], acc[m][n], 0, 0, 0);
                acc[m][n] = __builtin_amdgcn_mfma_f32_16x16x32_bf16(Al[m], Bh[n], acc[m][n], 0, 0, 0);
            }
    }
#pragma unroll
    for (int m = 0; m < 4; ++m)
#pragma unroll
        for (int r = 0; r < 4; ++r) {
            int row = (mtb + m) * 16 + (lane >> 4) * 4 + r;
#pragma unroll
            for (int n = 0; n < 4; ++n) {
                int col = (ntb + n) * 16 + (lane & 15);
                float v = acc[m][n][r];
                if (Ch) {
                    if (psplit)
                        Ch[((size_t)(col >> 7) * NCELL + row) * H + (col & 127)] = f2bf(v);
                    else
                        Ch[(size_t)row * ldc + col] = f2bf(v);
                } else {
                    Cf[(size_t)row * ldc + col] = v;
                }
            }
        }
}

// ---------------- fused per-edge MLP; transposed L2/L3 writeback; pk-fp16 atomics ----------------
__global__ __launch_bounds__(256, 4) void k_edge(const int* __restrict__ edges,
                                                 const u16* __restrict__ P,   // P9 layout
                                                 const u16* __restrict__ Ps0,
                                                 const u16* __restrict__ WF,
                                                 const float* __restrict__ bb1,
                                                 const float* __restrict__ bb2,
                                                 const float* __restrict__ bb3,
                                                 const float* __restrict__ bb4,
                                                 __half* __restrict__ msg) {
    __shared__ u16 zh[EB * H];    // 32KB, 16B-chunk XOR swizzle
    __shared__ int sdst[EB];
    int tid = threadIdx.x;
    int w = tid >> 6, lane = tid & 63;
    int bid = blockIdx.x;
    int t = bid >> 10, tile = bid & 1023;
    int ebase = tile * EB;

    // ---- layer 1 (per-type P9 gathers) ----
    {
        int row = tid >> 1, half = tid & 1;
        int e = ebase + row;
        int sn = edges[(t * 2) * NE + e];
        int dn = edges[(t * 2 + 1) * NE + e];
        if (half == 0) sdst[row] = dn;
        const u16* ps = (t == 0) ? Ps0 + (size_t)sn * H
                                 : P + ((size_t)(t + 4) * NCELL + sn) * H;
        const u16* pd = P + ((size_t)t * NCELL + dn) * H;
        const float* bb = bb1 + t * H;
#pragma unroll
        for (int cc = 0; cc < 8; ++cc) {
            int c8 = half * 8 + cc;
            ushort8 a = *reinterpret_cast<const ushort8*>(ps + c8 * 8);
            ushort8 d = *reinterpret_cast<const ushort8*>(pd + c8 * 8);
            float4 b0 = *reinterpret_cast<const float4*>(bb + c8 * 8);
            float4 b1v = *reinterpret_cast<const float4*>(bb + c8 * 8 + 4);
            float bv[8] = {b0.x, b0.y, b0.z, b0.w, b1v.x, b1v.y, b1v.z, b1v.w};
            ushort8 hh;
#pragma unroll
            for (int i = 0; i < 8; ++i)
                hh[i] = f2bf(fmaxf(bf2f(a[i]) + bf2f(d[i]) + bv[i], 0.f));
            *reinterpret_cast<ushort8*>(&zh[row * H + ((c8 ^ (row & 7)) << 3)]) = hh;
        }
    }
    __syncthreads();

    const u16* wfbase = WF + (size_t)(t * 3) * 32768;
    short8 Bh[2][4], Bl[2][4];

    // ---- layers 2,3: transposed compute mfma(W,z) -> lane holds 4 consecutive
    // features of one edge -> packed ds_write_b64 writeback ----
#pragma unroll 1
    for (int l = 0; l < 2; ++l) {
        const u16* wl = wfbase + l * 32768;
#pragma unroll
        for (int fg = 0; fg < 2; ++fg)
#pragma unroll
            for (int ks = 0; ks < 4; ++ks) {
                int nt = 2 * w + fg;
                Bh[fg][ks] = *reinterpret_cast<const short8*>(wl + ((nt * 4 + ks) * 64 + lane) * 8);
                Bl[fg][ks] = *reinterpret_cast<const short8*>(wl + ((32 + nt * 4 + ks) * 64 + lane) * 8);
            }
        f32x4 acc[8][2];
#pragma unroll
        for (int et = 0; et < 8; ++et)
#pragma unroll
            for (int fg = 0; fg < 2; ++fg)
                acc[et][fg] = (f32x4){0.f, 0.f, 0.f, 0.f};
#pragma unroll
        for (int et = 0; et < 8; ++et) {
            short8 Zf[4];
            int rr = et * 16 + (lane & 15);
#pragma unroll
            for (int ks = 0; ks < 4; ++ks) {
                int ch = ks * 4 + (lane >> 4);
                Zf[ks] = *reinterpret_cast<const short8*>(&zh[rr * H + ((ch ^ (rr & 7)) << 3)]);
            }
#pragma unroll
            for (int fg = 0; fg < 2; ++fg)
#pragma unroll
                for (int ks = 0; ks < 4; ++ks) {
                    acc[et][fg] = __builtin_amdgcn_mfma_f32_16x16x32_bf16(Bh[fg][ks], Zf[ks], acc[et][fg], 0, 0, 0);
                    acc[et][fg] = __builtin_amdgcn_mfma_f32_16x16x32_bf16(Bl[fg][ks], Zf[ks], acc[et][fg], 0, 0, 0);
                }
        }
        __syncthreads();   // all reads of zh done
        const float* bb = (l == 0 ? bb2 : bb3) + t * H;
        float bi[2][4];
#pragma unroll
        for (int fg = 0; fg < 2; ++fg)
#pragma unroll
            for (int r = 0; r < 4; ++r)
                bi[fg][r] = bb[(2 * w + fg) * 16 + (lane >> 4) * 4 + r];
#pragma unroll
        for (int et = 0; et < 8; ++et) {
            int e = et * 16 + (lane & 15);
#pragma unroll
            for (int fg = 0; fg < 2; ++fg) {
                int f0 = (2 * w + fg) * 16 + (lane >> 4) * 4;
                ushort4v v;
#pragma unroll
                for (int r = 0; r < 4; ++r)
                    v[r] = f2bf(fmaxf(acc[et][fg][r] + bi[fg][r], 0.f));
                int off = e * H + (((f0 >> 3) ^ (e & 7)) << 3) + (f0 & 7);
                *reinterpret_cast<ushort4v*>(&zh[off]) = v;
            }
        }
        __syncthreads();   // writes visible
    }

    // ---- layer 4: normal orientation, per-mt MFMA + packed-fp16 atomic scatter ----
    {
        const u16* wl = wfbase + 2 * 32768;
#pragma unroll
        for (int ng = 0; ng < 2; ++ng)
#pragma unroll
            for (int ks = 0; ks < 4; ++ks) {
                int nt = 2 * w + ng;
                Bh[ng][ks] = *reinterpret_cast<const short8*>(wl + ((nt * 4 + ks) * 64 + lane) * 8);
                Bl[ng][ks] = *reinterpret_cast<const short8*>(wl + ((32 + nt * 4 + ks) * 64 + lane) * 8);
            }
        const float* bb = bb4 + t * H;
        float bi[2];
#pragma unroll
        for (int ng = 0; ng < 2; ++ng) bi[ng] = bb[(2 * w + ng) * 16 + (lane & 15)];
        // permuted column pair base for this lane: features (2w)*16+c and (2w+1)*16+c
        int pos = (w * 16 + (lane & 15)) * 2;   // even -> 4B-aligned __half2
#pragma unroll 1
        for (int mt = 0; mt < 8; ++mt) {
            short8 Ah[4];
            int rr = mt * 16 + (lane & 15);
#pragma unroll
            for (int ks = 0; ks < 4; ++ks) {
                int ch = ks * 4 + (lane >> 4);
                Ah[ks] = *reinterpret_cast<const short8*>(&zh[rr * H + ((ch ^ (rr & 7)) << 3)]);
            }
            f32x4 a0 = (f32x4){0.f, 0.f, 0.f, 0.f};
            f32x4 a1 = (f32x4){0.f, 0.f, 0.f, 0.f};
#pragma unroll
            for (int ks = 0; ks < 4; ++ks) {
                a0 = __builtin_amdgcn_mfma_f32_16x16x32_bf16(Ah[ks], Bh[0][ks], a0, 0, 0, 0);
                a0 = __builtin_amdgcn_mfma_f32_16x16x32_bf16(Ah[ks], Bl[0][ks], a0, 0, 0, 0);
                a1 = __builtin_amdgcn_mfma_f32_16x16x32_bf16(Ah[ks], Bh[1][ks], a1, 0, 0, 0);
                a1 = __builtin_amdgcn_mfma_f32_16x16x32_bf16(Ah[ks], Bl[1][ks], a1, 0, 0, 0);
            }
#pragma unroll
            for (int r = 0; r < 4; ++r) {
                int d = sdst[mt * 16 + (lane >> 4) * 4 + r];
                __half2* mp = reinterpret_cast<__half2*>(msg + (size_t)d * MSGW + t * H + pos);
                unsafeAtomicAdd(mp, __floats2half2_rn(a0[r] + bi[0], a1[r] + bi[1]));
            }
        }
    }
}

// ---------------- LSTM pointwise + h frag pack (kt 24:28) ----------------
__global__ __launch_bounds__(256) void k_lstm(const float* __restrict__ gates,
                                              float* __restrict__ cst,
                                              float* __restrict__ rnn_h,
                                              u16* __restrict__ Ap, size_t aplane) {
    __shared__ float sh[16][132];
    int mtile = blockIdx.x, tid = threadIdx.x;
#pragma unroll
    for (int e = 0; e < 8; ++e) {
        int idx = e * 256 + tid;
        int row = idx >> 7, c = idx & 127;
        int grow = mtile * 16 + row;
        const float* g = gates + (size_t)grow * G4;
        float ig = g[c], fg = g[128 + c], gg = g[256 + c], og = g[384 + c];
        size_t ci = (size_t)grow * H + c;
        float c_old = cst[ci];
        float i_s = 1.f / (1.f + expf(-ig));
        float f_s = 1.f / (1.f + expf(-fg));
        float o_s = 1.f / (1.f + expf(-og));
        float c_new = f_s * c_old + i_s * tanhf(gg);
        float h_new = o_s * tanhf(c_new);
        cst[ci] = c_new;
        rnn_h[ci] = h_new;
        sh[row][c] = h_new;
    }
    __syncthreads();
    int kt = tid >> 6, lane = tid & 63;
    int row = lane & 15, c0 = kt * 32 + ((lane >> 4) << 3);
    ushort8 hh, ll;
#pragma unroll
    for (int i = 0; i < 8; ++i) {
        float x = sh[row][c0 + i];
        u16 h = f2bf(x);
        hh[i] = h;
        ll[i] = f2bf(x - bf2f(h));
    }
    size_t fo = ((size_t)(mtile * AKT + 24 + kt) * 64 + lane) * 8;
    *reinterpret_cast<ushort8*>(Ap + fo) = hh;
    *reinterpret_cast<ushort8*>(Ap + aplane + fo) = ll;
}

// ---------------- logits ----------------
__global__ __launch_bounds__(256) void k_logits(const float* __restrict__ h,
                                                const float* __restrict__ oemb,
                                                float* __restrict__ out) {
    __shared__ float oe[17][129];
    int b = blockIdx.x, tid = threadIdx.x;
    for (int id = tid; id < 17 * 128; id += 256) {
        int r = id >> 7, c = id & 127;
        oe[r][c] = oemb[(b * 17 + r) * H + c];
    }
    __syncthreads();
    const float* hr = h + (size_t)(b * 256 + tid) * H;
    float acc[17] = {};
    for (int v = 0; v < 32; ++v) {
        float4 hv = reinterpret_cast<const float4*>(hr)[v];
#pragma unroll
        for (int cls = 0; cls < 17; ++cls) {
            acc[cls] = fmaf(hv.x, oe[cls][v * 4 + 0],
                       fmaf(hv.y, oe[cls][v * 4 + 1],
                       fmaf(hv.z, oe[cls][v * 4 + 2],
                       fmaf(hv.w, oe[cls][v * 4 + 3], acc[cls]))));
        }
    }
    float* op = out + (size_t)(b * 256 + tid) * 17;
#pragma unroll
    for (int cls = 0; cls < 17; ++cls) op[cls] = acc[cls];
}

extern "C" void kernel_launch(void* const* d_in, const int* in_sizes, int n_in,
                              void* d_out, int out_size, void* d_ws, size_t ws_size,
                              hipStream_t stream) {
    (void)in_sizes; (void)n_in; (void)out_size; (void)ws_size;
    const int*   edges = (const int*)d_in[0];
    const int*   q     = (const int*)d_in[1];
    const float* emb   = (const float*)d_in[2];
    const float* oemb  = (const float*)d_in[3];
    const float* W1    = (const float*)d_in[4];
    const float* b1    = (const float*)d_in[5];
    const float* W2    = (const float*)d_in[6];
    const float* b2    = (const float*)d_in[7];
    const float* W3    = (const float*)d_in[8];
    const float* b3    = (const float*)d_in[9];
    const float* W4    = (const float*)d_in[10];
    const float* b4    = (const float*)d_in[11];
    const float* Wih   = (const float*)d_in[12];
    const float* Whh   = (const float*)d_in[13];
    float* out = (float*)d_out;

    // ---- workspace layout (bytes, 256-aligned) ----
    char* wsp = (char*)d_ws;
    size_t off = 0;
    auto alloc = [&](size_t bytes) { void* p = wsp + off; off = (off + bytes + 255) & ~(size_t)255; return p; };
    __half* msg   = (__half*)alloc((size_t)NCELL * MSGW * 2);       // 21MB fp16
    u16*   P      = (u16*)  alloc((size_t)9 * NCELL * H * 2);       // 37.7MB (P9 layout)
    float* gates  = (float*)P;                                      // alias
    float* rnn_h  = (float*)alloc((size_t)NCELL * H * 4);
    float* cst    = (float*)alloc((size_t)NCELL * H * 4);
    u16*   Ps0    = (u16*)  alloc((size_t)NCLU * H * 2);
    float* avg    = (float*)alloc((size_t)64 * H * 4);
    size_t aplane = (size_t)NCELL * 896;
    u16*   Ap     = (u16*)  alloc(aplane * 2 * 2);
    u16*   WF     = (u16*)  alloc((size_t)983040 * 2);
    size_t bwpl   = (size_t)512 * 896;
    u16*   Bw     = (u16*)  alloc(bwpl * 2 * 2);
    size_t bppl   = (size_t)1152 * 128;
    u16*   Bp     = (u16*)  alloc(bppl * 2 * 2);

    // ---- one-time prep ----
    k_avg<<<64, 128, 0, stream>>>(emb, avg);
    k_init<<<1024, 256, 0, stream>>>(q, emb, avg, Ap, aplane, rnn_h, cst);
    k_prepw<<<240, 256, 0, stream>>>(W2, W3, W4, WF);
    {
        dim3 g(32, 7);
        k_packBw<<<g, 256, 0, stream>>>(Wih, Whh, Bw, bwpl);
    }
    k_packBp<<<72, 256, 0, stream>>>(W1, Bp, bppl);
    {
        dim3 g0(17, 2);
        k_gemm32<<<g0, 256, 0, stream>>>(emb, H, W1, H, Ps0, H, H);
    }

    for (int s = 0; s < SSTEPS; ++s) {
        k_zeromsg<<<NCELL * MSGW / 8 / 256, 256, 0, stream>>>(msg);
        // P9 = h @ Wproj (bf16, per-type layout); A-frags kt 0:4 (cell_x) at s=0 else 24:28 (h)
        {
            dim3 g(128, 9);
            k_gemm_bf<<<g, 256, 0, stream>>>(Ap, aplane, (s == 0) ? 0 : 24,
                                             Bp, bppl, 4, 4, nullptr, P, H, 1);
        }
        k_edge<<<NT * (NE / EB), 256, 0, stream>>>(edges, P, Ps0, WF,
                                                   b1, b2, b3, b4, msg);
        {
            dim3 g(1024, 5);
            k_packmsg<<<g, 256, 0, stream>>>(msg, Ap, aplane);
        }
        // gates = [cell_x, msg, h] @ [Wih; Whh]  (K = 768 at s=0, 896 else)
        {
            dim3 g(128, 4);
            k_gemm_bf<<<g, 256, 0, stream>>>(Ap, aplane, 0, Bw, bwpl, AKT,
                                             (s == 0) ? 24 : 28, gates, nullptr, G4, 0);
        }
        k_lstm<<<1024, 256, 0, stream>>>(gates, cst, rnn_h, Ap, aplane);
        k_logits<<<64, 256, 0, stream>>>(rnn_h, oemb, out + (size_t)s * NCELL * 17);
    }
}